// Round 2
// baseline (3232.884 us; speedup 1.0000x reference)
//
#include <hip/hip_runtime.h>
#include <hip/hip_bf16.h>
#include <math.h>

#define EMB 768
#define NTOK 654
#define NPATCH 576
#define NTEXT 77
#define NBATCH 32
#define HD 384
#define MROWS (NBATCH * NTOK)   // 20928
#define LN_EPS 1e-5f
#define INV_SQRT_EMB 0.03608439182435161f

typedef unsigned int u32;
typedef unsigned short u16;

// ---------------- small helpers ----------------
__device__ __forceinline__ float bf2f(u16 u) {
    union { u32 i; float f; } x; x.i = ((u32)u) << 16; return x.f;
}
__device__ __forceinline__ float2 bfx2(u32 u) {
    union { u32 i; float f; } a, b;
    a.i = (u & 0xffffu) << 16; b.i = u & 0xffff0000u;
    return make_float2(a.f, b.f);
}
__device__ __forceinline__ u16 f2bf(float f) {  // round-to-nearest-even
    union { float f; u32 i; } x; x.f = f;
    u32 r = x.i + 0x7fffu + ((x.i >> 16) & 1u);
    return (u16)(r >> 16);
}

__device__ __forceinline__ float blk_sum(float v, float* red, int tid) {
    red[tid] = v; __syncthreads();
    #pragma unroll
    for (int s = 128; s > 0; s >>= 1) {
        if (tid < s) red[tid] += red[tid + s];
        __syncthreads();
    }
    float r = red[0]; __syncthreads();
    return r;
}

// ---------------- fill cls + text rows of t ----------------
__global__ __launch_bounds__(256)
void fill_rows_kernel(const float* __restrict__ cls, const float* __restrict__ text,
                      float* __restrict__ t)
{
    const int b = blockIdx.y, r = blockIdx.x;  // r in [0,78)
    const int tid = threadIdx.x;
    const long trow = (long)b * NTOK + (r == 0 ? 0 : NPATCH + r);
    const float* src = (r == 0) ? cls : text + ((long)b * NTEXT + (r - 1)) * EMB;
    float* dst = t + trow * EMB;
    #pragma unroll
    for (int s = 0; s < 3; s++) dst[tid + s * 256] = src[tid + s * 256];
}

// ---------------- patch-embed GEMM (gathered A, fp32) ----------------
__global__ __launch_bounds__(256)
void patch_gemm(const float* __restrict__ x, const float* __restrict__ Wpa,
                const float* __restrict__ bpa, float* __restrict__ t)
{
    __shared__ float As[16][128];
    __shared__ float Bs[16][128];
    const int m0 = blockIdx.y * 128, n0 = blockIdx.x * 128;
    const int tid = threadIdx.x, tr = tid >> 4, tc = tid & 15;
    const int srow = tid >> 1, sseg = tid & 1;
    const int brow = tid >> 4, bseg = tid & 15;
    float acc[8][8] = {};
    const int r = m0 + srow;                  // M = 18432, multiple of 128
    const int bb = r / NPATCH, pidx = r % NPATCH;
    const int hh = pidx / 24, ww = pidx % 24;

    for (int k0 = 0; k0 < EMB; k0 += 16) {
        const int kb = k0 + sseg * 8;
        #pragma unroll
        for (int j = 0; j < 8; j++) {
            const int kk = kb + j;
            const int cc = kk % 3, p12 = kk / 3, p1 = p12 >> 4, p2 = p12 & 15;
            As[sseg * 8 + j][srow] =
                x[((long)(bb * 3 + cc) * 384 + hh * 16 + p1) * 384 + ww * 16 + p2];
        }
        const float* p = Wpa + (long)(k0 + brow) * EMB + n0 + bseg * 8;
        *(float4*)&Bs[brow][bseg * 8]     = *(const float4*)p;
        *(float4*)&Bs[brow][bseg * 8 + 4] = *(const float4*)(p + 4);
        __syncthreads();
        #pragma unroll
        for (int kk = 0; kk < 16; kk++) {
            float ar[8], br[8];
            *(float4*)&ar[0] = *(const float4*)&As[kk][tr * 8];
            *(float4*)&ar[4] = *(const float4*)&As[kk][tr * 8 + 4];
            *(float4*)&br[0] = *(const float4*)&Bs[kk][tc * 8];
            *(float4*)&br[4] = *(const float4*)&Bs[kk][tc * 8 + 4];
            #pragma unroll
            for (int i = 0; i < 8; i++)
                #pragma unroll
                for (int j = 0; j < 8; j++) acc[i][j] += ar[i] * br[j];
        }
        __syncthreads();
    }
    #pragma unroll
    for (int i = 0; i < 8; i++) {
        const int rr = m0 + tr * 8 + i;
        const int b2 = rr / NPATCH, pr = rr % NPATCH;
        float* cp = t + ((long)b2 * NTOK + 1 + pr) * EMB;
        #pragma unroll
        for (int j = 0; j < 8; j++) {
            const int cc = n0 + tc * 8 + j;
            cp[cc] = acc[i][j] + bpa[cc];
        }
    }
}

// ---------------- per-row LN stats of t ----------------
__global__ __launch_bounds__(256)
void ln_stats_kernel(const float* __restrict__ in, float* __restrict__ mu,
                     float* __restrict__ rsd)
{
    __shared__ float red[256];
    const int row = blockIdx.x, tid = threadIdx.x;
    const float* x = in + (long)row * EMB;
    const float v0 = x[tid], v1 = x[tid + 256], v2 = x[tid + 512];
    const float m = blk_sum(v0 + v1 + v2, red, tid) * (1.f / EMB);
    const float d0 = v0 - m, d1 = v1 - m, d2 = v2 - m;
    const float var = blk_sum(d0 * d0 + d1 * d1 + d2 * d2, red, tid) * (1.f / EMB);
    if (tid == 0) { mu[row] = m; rsd[row] = rsqrtf(var + LN_EPS); }
}

// ---------------- QKV GEMM: A = LN1(t) fused, out bf16; z selects Q/K/V ----------------
__global__ __launch_bounds__(256)
void qkv_gemm(const float* __restrict__ tbuf, const float* __restrict__ mu,
              const float* __restrict__ rsd,
              const float* __restrict__ g1, const float* __restrict__ be1,
              const float* __restrict__ Wq, const float* __restrict__ Wk,
              const float* __restrict__ Wv,
              const float* __restrict__ bq, const float* __restrict__ bk,
              const float* __restrict__ bv,
              u16* __restrict__ qo, u16* __restrict__ ko, u16* __restrict__ vo)
{
    __shared__ float As[16][128];
    __shared__ float Bs[16][128];
    __shared__ float gS[EMB], beS[EMB];
    const int z = blockIdx.z;
    const float* Bw   = (z == 0) ? Wq : (z == 1) ? Wk : Wv;
    const float* bias = (z == 0) ? bq : (z == 1) ? bk : bv;
    u16* C            = (z == 0) ? qo : (z == 1) ? ko : vo;
    const int m0 = blockIdx.y * 128, n0 = blockIdx.x * 128;
    const int tid = threadIdx.x, tr = tid >> 4, tc = tid & 15;
    const int srow = tid >> 1, sseg = tid & 1;
    const int brow = tid >> 4, bseg = tid & 15;

    for (int i = tid; i < EMB; i += 256) { gS[i] = g1[i]; beS[i] = be1[i]; }

    const int r = m0 + srow;
    float mu_r = 0.f, rs_r = 0.f;
    if (r < MROWS) { mu_r = mu[r]; rs_r = rsd[r]; }
    float acc[8][8] = {};
    __syncthreads();

    for (int k0 = 0; k0 < EMB; k0 += 16) {
        const int kb = k0 + sseg * 8;
        if (r < MROWS) {
            const float* p = tbuf + (long)r * EMB + kb;
            const float4 u0 = *(const float4*)p, u1 = *(const float4*)(p + 4);
            const float tv[8] = {u0.x, u0.y, u0.z, u0.w, u1.x, u1.y, u1.z, u1.w};
            #pragma unroll
            for (int j = 0; j < 8; j++)
                As[sseg * 8 + j][srow] = (tv[j] - mu_r) * rs_r * gS[kb + j] + beS[kb + j];
        } else {
            #pragma unroll
            for (int j = 0; j < 8; j++) As[sseg * 8 + j][srow] = 0.f;
        }
        const float* p2 = Bw + (long)(k0 + brow) * EMB + n0 + bseg * 8;
        *(float4*)&Bs[brow][bseg * 8]     = *(const float4*)p2;
        *(float4*)&Bs[brow][bseg * 8 + 4] = *(const float4*)(p2 + 4);
        __syncthreads();
        #pragma unroll
        for (int kk = 0; kk < 16; kk++) {
            float ar[8], br[8];
            *(float4*)&ar[0] = *(const float4*)&As[kk][tr * 8];
            *(float4*)&ar[4] = *(const float4*)&As[kk][tr * 8 + 4];
            *(float4*)&br[0] = *(const float4*)&Bs[kk][tc * 8];
            *(float4*)&br[4] = *(const float4*)&Bs[kk][tc * 8 + 4];
            #pragma unroll
            for (int i = 0; i < 8; i++)
                #pragma unroll
                for (int j = 0; j < 8; j++) acc[i][j] += ar[i] * br[j];
        }
        __syncthreads();
    }
    #pragma unroll
    for (int i = 0; i < 8; i++) {
        const int rr = m0 + tr * 8 + i;
        if (rr >= MROWS) continue;
        u16* cp = C + (long)rr * EMB;
        #pragma unroll
        for (int j = 0; j < 8; j++) {
            const int cc = n0 + tc * 8 + j;
            cp[cc] = f2bf(acc[i][j] + bias[cc]);
        }
    }
}

// ---------------- proj GEMM: A bf16 (attn out), out fp32 ----------------
__global__ __launch_bounds__(256)
void proj_gemm(const u16* __restrict__ Abf, const float* __restrict__ Bw,
               const float* __restrict__ bias, float* __restrict__ C)
{
    __shared__ float As[16][128];
    __shared__ float Bs[16][128];
    const int m0 = blockIdx.y * 128, n0 = blockIdx.x * 128;
    const int tid = threadIdx.x, tr = tid >> 4, tc = tid & 15;
    const int srow = tid >> 1, sseg = tid & 1;
    const int brow = tid >> 4, bseg = tid & 15;
    const int r = m0 + srow;
    float acc[8][8] = {};

    for (int k0 = 0; k0 < EMB; k0 += 16) {
        const int kb = k0 + sseg * 8;
        if (r < MROWS) {
            const uint4 u = *(const uint4*)(Abf + (long)r * EMB + kb);
            const float2 f0 = bfx2(u.x), f1 = bfx2(u.y), f2v = bfx2(u.z), f3 = bfx2(u.w);
            As[sseg * 8 + 0][srow] = f0.x; As[sseg * 8 + 1][srow] = f0.y;
            As[sseg * 8 + 2][srow] = f1.x; As[sseg * 8 + 3][srow] = f1.y;
            As[sseg * 8 + 4][srow] = f2v.x; As[sseg * 8 + 5][srow] = f2v.y;
            As[sseg * 8 + 6][srow] = f3.x; As[sseg * 8 + 7][srow] = f3.y;
        } else {
            #pragma unroll
            for (int j = 0; j < 8; j++) As[sseg * 8 + j][srow] = 0.f;
        }
        const float* p2 = Bw + (long)(k0 + brow) * EMB + n0 + bseg * 8;
        *(float4*)&Bs[brow][bseg * 8]     = *(const float4*)p2;
        *(float4*)&Bs[brow][bseg * 8 + 4] = *(const float4*)(p2 + 4);
        __syncthreads();
        #pragma unroll
        for (int kk = 0; kk < 16; kk++) {
            float ar[8], br[8];
            *(float4*)&ar[0] = *(const float4*)&As[kk][tr * 8];
            *(float4*)&ar[4] = *(const float4*)&As[kk][tr * 8 + 4];
            *(float4*)&br[0] = *(const float4*)&Bs[kk][tc * 8];
            *(float4*)&br[4] = *(const float4*)&Bs[kk][tc * 8 + 4];
            #pragma unroll
            for (int i = 0; i < 8; i++)
                #pragma unroll
                for (int j = 0; j < 8; j++) acc[i][j] += ar[i] * br[j];
        }
        __syncthreads();
    }
    #pragma unroll
    for (int i = 0; i < 8; i++) {
        const int rr = m0 + tr * 8 + i;
        if (rr >= MROWS) continue;
        float* cp = C + (long)rr * EMB;
        #pragma unroll
        for (int j = 0; j < 8; j++) {
            const int cc = n0 + tc * 8 + j;
            cp[cc] = acc[i][j] + bias[cc];
        }
    }
}

// ---------------- flash attention: q,k,v bf16 -> o bf16 (in-place over q) ----------------
// Per block: one (b, head, 32 q-rows). Online softmax over 21 kv-tiles of 32.
// No pre-softmax scale; 1/sqrt(768) applied at the end. LDS passed dynamically.
#define QT 32
#define KT 32
#define QSLD 394   // 384 + 10 pad: row stride 197 words (odd) -> conflict-free reads
#define VSLD 392   // 384 + 8 pad: 16B-aligned rows for b128
#define SSLD 36

__global__ __launch_bounds__(256)
void flash_attn(const u16* __restrict__ q, const u16* __restrict__ k,
                const u16* __restrict__ v, u16* __restrict__ o)
{
    extern __shared__ char smem[];
    u16* Qs = (u16*)smem;                    // [QT][QSLD]
    u16* Ks = Qs + QT * QSLD;                // [KT][QSLD]
    u16* Vs = Ks + KT * QSLD;                // [KT][VSLD]
    float* Ss = (float*)(Vs + KT * VSLD);    // [QT][SSLD]
#define QS_(i,j) Qs[(i) * QSLD + (j)]
#define KS_(i,j) Ks[(i) * QSLD + (j)]
#define VS_(i,j) Vs[(i) * VSLD + (j)]
#define SS_(i,j) Ss[(i) * SSLD + (j)]

    const int bh = blockIdx.y, b = bh >> 1, h = bh & 1;
    const int q0 = blockIdx.x * QT;
    const int tid = threadIdx.x;
    const int row = tid >> 3, c = tid & 7;   // staging / softmax / PV mapping
    const int ti = tid >> 4, tj = tid & 15;  // scores 2x2 micro mapping
    const long base = (long)b * NTOK * EMB + (long)h * HD;

    // stage Q tile (zero-fill invalid rows)
    {
        const int r = q0 + row;
        if (r < NTOK) {
            const u16* src = q + base + (long)r * EMB + c * 48;
            #pragma unroll
            for (int g = 0; g < 6; g++) {
                const uint4 u = *(const uint4*)(src + g * 8);
                u32* dst = (u32*)&QS_(row, c * 48 + g * 8);
                dst[0] = u.x; dst[1] = u.y; dst[2] = u.z; dst[3] = u.w;
            }
        } else {
            #pragma unroll
            for (int g = 0; g < 6; g++) {
                u32* dst = (u32*)&QS_(row, c * 48 + g * 8);
                dst[0] = 0; dst[1] = 0; dst[2] = 0; dst[3] = 0;
            }
        }
    }

    float m_run = -3.0e38f, l_run = 0.f;
    float oacc[48];
    #pragma unroll
    for (int i = 0; i < 48; i++) oacc[i] = 0.f;

    const int NKT = (NTOK + KT - 1) / KT;    // 21
    for (int kt = 0; kt < NKT; kt++) {
        const int kv0 = kt * KT;
        __syncthreads();  // protect Ks/Vs/Ss from previous iteration's readers

        // stage K,V tiles (zero-fill invalid keys)
        {
            const int r = kv0 + row;
            if (r < NTOK) {
                const u16* ks = k + base + (long)r * EMB + c * 48;
                const u16* vs = v + base + (long)r * EMB + c * 48;
                #pragma unroll
                for (int g = 0; g < 6; g++) {
                    const uint4 u = *(const uint4*)(ks + g * 8);
                    u32* dst = (u32*)&KS_(row, c * 48 + g * 8);
                    dst[0] = u.x; dst[1] = u.y; dst[2] = u.z; dst[3] = u.w;
                    *(uint4*)&VS_(row, c * 48 + g * 8) = *(const uint4*)(vs + g * 8);
                }
            } else {
                #pragma unroll
                for (int g = 0; g < 6; g++) {
                    u32* dst = (u32*)&KS_(row, c * 48 + g * 8);
                    dst[0] = 0; dst[1] = 0; dst[2] = 0; dst[3] = 0;
                    *(uint4*)&VS_(row, c * 48 + g * 8) = make_uint4(0, 0, 0, 0);
                }
            }
        }
        __syncthreads();

        // scores S = Q K^T, 2x2 micro-tile per thread
        const int i0 = ti * 2, j0 = tj * 2;
        float s00 = 0.f, s01 = 0.f, s10 = 0.f, s11 = 0.f;
        #pragma unroll 8
        for (int kk = 0; kk < HD; kk += 2) {
            const float2 qa = bfx2(*(const u32*)&QS_(i0, kk));
            const float2 qb = bfx2(*(const u32*)&QS_(i0 + 1, kk));
            const float2 ka = bfx2(*(const u32*)&KS_(j0, kk));
            const float2 kb = bfx2(*(const u32*)&KS_(j0 + 1, kk));
            s00 += qa.x * ka.x + qa.y * ka.y;
            s01 += qa.x * kb.x + qa.y * kb.y;
            s10 += qb.x * ka.x + qb.y * ka.y;
            s11 += qb.x * kb.x + qb.y * kb.y;
        }
        const bool ok0 = (kv0 + j0) < NTOK, ok1 = (kv0 + j0 + 1) < NTOK;
        SS_(i0, j0)         = ok0 ? s00 : -1e30f;
        SS_(i0, j0 + 1)     = ok1 ? s01 : -1e30f;
        SS_(i0 + 1, j0)     = ok0 ? s10 : -1e30f;
        SS_(i0 + 1, j0 + 1) = ok1 ? s11 : -1e30f;
        __syncthreads();

        // online softmax per row (8 threads/row, 4 elems each)
        float sv[4];
        float tmax = -3.0e38f;
        #pragma unroll
        for (int e = 0; e < 4; e++) { sv[e] = SS_(row, c + 8 * e); tmax = fmaxf(tmax, sv[e]); }
        #pragma unroll
        for (int off = 1; off < 8; off <<= 1) tmax = fmaxf(tmax, __shfl_xor(tmax, off, 64));
        const float m_new = fmaxf(m_run, tmax);
        const float corr = __expf(m_run - m_new);
        float psum = 0.f;
        #pragma unroll
        for (int e = 0; e < 4; e++) { sv[e] = __expf(sv[e] - m_new); psum += sv[e]; }
        #pragma unroll
        for (int off = 1; off < 8; off <<= 1) psum += __shfl_xor(psum, off, 64);
        l_run = l_run * corr + psum;
        m_run = m_new;
        #pragma unroll
        for (int e = 0; e < 4; e++) SS_(row, c + 8 * e) = sv[e];
        __syncthreads();

        // PV accumulate: oacc = oacc*corr + P @ V  (thread owns row, d = c*48..+48)
        #pragma unroll
        for (int i = 0; i < 48; i++) oacc[i] *= corr;
        for (int kk = 0; kk < KT; kk++) {
            const float p = SS_(row, kk);
            const u16* vr = &VS_(kk, c * 48);
            #pragma unroll
            for (int g = 0; g < 6; g++) {
                const uint4 u = *(const uint4*)(vr + g * 8);
                const float2 a0 = bfx2(u.x), a1 = bfx2(u.y), a2 = bfx2(u.z), a3 = bfx2(u.w);
                oacc[g * 8 + 0] += p * a0.x; oacc[g * 8 + 1] += p * a0.y;
                oacc[g * 8 + 2] += p * a1.x; oacc[g * 8 + 3] += p * a1.y;
                oacc[g * 8 + 4] += p * a2.x; oacc[g * 8 + 5] += p * a2.y;
                oacc[g * 8 + 6] += p * a3.x; oacc[g * 8 + 7] += p * a3.y;
            }
        }
    }

    // write O (scaled by 1/(l*sqrt(768))) in-place over the q tile
    const int r = q0 + row;
    if (r < NTOK) {
        const float sc = INV_SQRT_EMB / l_run;
        u16* dst = o + base + (long)r * EMB + c * 48;
        #pragma unroll
        for (int g = 0; g < 6; g++) {
            union { u16 s[8]; uint4 v4; } tmp;
            #pragma unroll
            for (int e = 0; e < 8; e++) tmp.s[e] = f2bf(oacc[g * 8 + e] * sc);
            *(uint4*)(dst + g * 8) = tmp.v4;
        }
    }
#undef QS_
#undef KS_
#undef VS_
#undef SS_
}

// ---------------- LN2 then residual-add into t ----------------
__global__ __launch_bounds__(256)
void ln_add_kernel(const float* __restrict__ in, float* __restrict__ t,
                   const float* __restrict__ g, const float* __restrict__ be)
{
    __shared__ float red[256];
    const int row = blockIdx.x, tid = threadIdx.x;
    const float* x = in + (long)row * EMB;
    const float v0 = x[tid], v1 = x[tid + 256], v2 = x[tid + 512];
    const float mu = blk_sum(v0 + v1 + v2, red, tid) * (1.f / EMB);
    const float d0 = v0 - mu, d1 = v1 - mu, d2 = v2 - mu;
    const float var = blk_sum(d0 * d0 + d1 * d1 + d2 * d2, red, tid) * (1.f / EMB);
    const float rs = rsqrtf(var + LN_EPS);
    float* o = t + (long)row * EMB;
    o[tid]       += d0 * rs * g[tid]       + be[tid];
    o[tid + 256] += d1 * rs * g[tid + 256] + be[tid + 256];
    o[tid + 512] += d2 * rs * g[tid + 512] + be[tid + 512];
}

// ---------------- mean over tokens ----------------
__global__ __launch_bounds__(128)
void meanpool_kernel(const float* __restrict__ t, float* __restrict__ m)
{
    const int b = blockIdx.y;
    const int e = blockIdx.x * 128 + threadIdx.x;
    const float* p = t + (long)b * NTOK * EMB + e;
    float s = 0.f;
    for (int j = 0; j < NTOK; j++) s += p[(long)j * EMB];
    m[b * EMB + e] = s * (1.f / NTOK);
}

// ---------------- LN3 + final Linear ----------------
__global__ __launch_bounds__(256)
void final_kernel(const float* __restrict__ m, const float* __restrict__ g,
                  const float* __restrict__ be, const float* __restrict__ Wf,
                  const float* __restrict__ bf, float* __restrict__ out)
{
    __shared__ float red[256];
    __shared__ float mln[EMB];
    const int b = blockIdx.x, tid = threadIdx.x;
    const float* x = m + b * EMB;
    const float v0 = x[tid], v1 = x[tid + 256], v2 = x[tid + 512];
    const float mu = blk_sum(v0 + v1 + v2, red, tid) * (1.f / EMB);
    const float d0 = v0 - mu, d1 = v1 - mu, d2 = v2 - mu;
    const float var = blk_sum(d0 * d0 + d1 * d1 + d2 * d2, red, tid) * (1.f / EMB);
    const float rs = rsqrtf(var + LN_EPS);
    mln[tid]       = d0 * rs * g[tid]       + be[tid];
    mln[tid + 256] = d1 * rs * g[tid + 256] + be[tid + 256];
    mln[tid + 512] = d2 * rs * g[tid + 512] + be[tid + 512];
    __syncthreads();
    #pragma unroll
    for (int s = 0; s < 3; s++) {
        const int e = tid + s * 256;
        float acc = bf[e];
        #pragma unroll 8
        for (int k = 0; k < EMB; k++) acc += mln[k] * Wf[(long)k * EMB + e];
        out[(long)b * EMB + e] = acc;
    }
}

extern "C" void kernel_launch(void* const* d_in, const int* in_sizes, int n_in,
                              void* d_out, int out_size, void* d_ws, size_t ws_size,
                              hipStream_t stream) {
    const float* x      = (const float*)d_in[0];
    const float* text   = (const float*)d_in[1];
    const float* Wpatch = (const float*)d_in[2];
    const float* bpatch = (const float*)d_in[3];
    const float* cls    = (const float*)d_in[4];
    const float* g1  = (const float*)d_in[5];
    const float* be1 = (const float*)d_in[6];
    const float* Wq  = (const float*)d_in[7];
    const float* bq  = (const float*)d_in[8];
    const float* Wk  = (const float*)d_in[9];
    const float* bk  = (const float*)d_in[10];
    const float* Wv  = (const float*)d_in[11];
    const float* bv  = (const float*)d_in[12];
    const float* Wp  = (const float*)d_in[13];
    const float* bp  = (const float*)d_in[14];
    const float* g2  = (const float*)d_in[15];
    const float* be2 = (const float*)d_in[16];
    const float* g3  = (const float*)d_in[17];
    const float* be3 = (const float*)d_in[18];
    const float* Wf  = (const float*)d_in[19];
    const float* bf  = (const float*)d_in[20];

    // workspace layout (~161 MB total):
    //   [0, S)              t            fp32
    //   [S, S+Sh)           q (-> attn o) bf16
    //   [S+Sh, S+2Sh)       k            bf16
    //   [S+2Sh, S+3Sh)      v            bf16
    //   [S+Sh, S+3Sh)       o2 (fp32, overwrites k+v after attention)
    //   [S+3Sh, ...)        mu, rsd, mpool
    char* ws = (char*)d_ws;
    const size_t S  = (size_t)NBATCH * NTOK * EMB * 4;   // 64,290,816
    const size_t Sh = S / 2;
    float* t   = (float*)ws;
    u16*   qb  = (u16*)(ws + S);
    u16*   kbf = (u16*)(ws + S + Sh);
    u16*   vbf = (u16*)(ws + S + 2 * Sh);
    float* o2  = (float*)(ws + S + Sh);
    float* muv = (float*)(ws + S + 3 * Sh);
    float* rsv = muv + MROWS;
    float* mp  = rsv + MROWS;

    // 1) cls + text rows of t
    fill_rows_kernel<<<dim3(NTEXT + 1, NBATCH), 256, 0, stream>>>(cls, text, t);
    // 2) patch embed -> t rows 1..576 per batch
    patch_gemm<<<dim3(6, NBATCH * NPATCH / 128), 256, 0, stream>>>(x, Wpatch, bpatch, t);
    // 3) LN1 row stats
    ln_stats_kernel<<<MROWS, 256, 0, stream>>>(t, muv, rsv);
    // 4) QKV (LN1 fused into A-load), bf16 out
    qkv_gemm<<<dim3(6, (MROWS + 127) / 128, 3), 256, 0, stream>>>(
        t, muv, rsv, g1, be1, Wq, Wk, Wv, bq, bk, bv, qb, kbf, vbf);
    // 5) flash attention, o overwrites q in place
    const int flashLds = QT * QSLD * 2 + KT * QSLD * 2 + KT * VSLD * 2 + QT * SSLD * 4;
    flash_attn<<<dim3((NTOK + QT - 1) / QT, NBATCH * 2), 256, flashLds, stream>>>(
        qb, kbf, vbf, qb);
    // 6) proj: o2 = o @ Wp + bp (fp32, over dead k/v region)
    proj_gemm<<<dim3(6, (MROWS + 127) / 128), 256, 0, stream>>>(qb, Wp, bp, o2);
    // 7) t += LN2(o2)
    ln_add_kernel<<<MROWS, 256, 0, stream>>>(o2, t, g2, be2);
    // 8) mean pool
    meanpool_kernel<<<dim3(6, NBATCH), 128, 0, stream>>>(t, mp);
    // 9) LN3 + final linear
    final_kernel<<<NBATCH, 256, 0, stream>>>(mp, g3, be3, Wf, bf, (float*)d_out);
}

// Round 4
// 911.265 us; speedup vs baseline: 3.5477x; 3.5477x over previous
//
#include <hip/hip_runtime.h>
#include <hip/hip_bf16.h>
#include <math.h>

#define EMB 768
#define NTOK 654
#define NPATCH 576
#define NTEXT 77
#define NBATCH 32
#define HD 384
#define MROWS (NBATCH * NTOK)   // 20928
#define LN_EPS 1e-5f
#define INV_SQRT_EMB 0.03608439182435161f

typedef unsigned int u32;
typedef unsigned short u16;
typedef float f32x4 __attribute__((ext_vector_type(4)));
typedef __bf16 bf16x8 __attribute__((ext_vector_type(8)));

union BF8 { uint4 u4; u32 w[4]; bf16x8 v; };

// ---------------- helpers ----------------
__device__ __forceinline__ float bf2f(u16 u) {
    union { u32 i; float f; } x; x.i = ((u32)u) << 16; return x.f;
}
__device__ __forceinline__ u16 f2bf(float f) {  // RTNE
    union { float f; u32 i; } x; x.f = f;
    u32 r = x.i + 0x7fffu + ((x.i >> 16) & 1u);
    return (u16)(r >> 16);
}
__device__ __forceinline__ u32 pk2(float lo, float hi) {
    return (u32)f2bf(lo) | ((u32)f2bf(hi) << 16);
}
__device__ __forceinline__ float blk_sum(float v, float* red, int tid) {
    red[tid] = v; __syncthreads();
    #pragma unroll
    for (int s = 128; s > 0; s >>= 1) {
        if (tid < s) red[tid] += red[tid + s];
        __syncthreads();
    }
    float r = red[0]; __syncthreads();
    return r;
}
__device__ __forceinline__ f32x4 mfma16(bf16x8 a, bf16x8 b, f32x4 c) {
    return __builtin_amdgcn_mfma_f32_16x16x32_bf16(a, b, c, 0, 0, 0);
}

// ---------------- weight transpose + bf16: Wt[n][k] = bf16(W[k][n]) ----------------
__global__ __launch_bounds__(256)
void wt_kernel(const float* __restrict__ W0, const float* __restrict__ W1,
               const float* __restrict__ W2, const float* __restrict__ W3,
               const float* __restrict__ W4, u16* __restrict__ dst)
{
    __shared__ float tile[32][33];
    const int z = blockIdx.z;
    const float* W = (z == 0) ? W0 : (z == 1) ? W1 : (z == 2) ? W2 : (z == 3) ? W3 : W4;
    u16* o = dst + (size_t)z * EMB * EMB;
    const int bi = blockIdx.y, bj = blockIdx.x;
    const int r = threadIdx.x >> 5, c = threadIdx.x & 31;
    #pragma unroll
    for (int i = 0; i < 4; i++)
        tile[r + i * 8][c] = W[(long)(bi * 32 + r + i * 8) * EMB + bj * 32 + c];
    __syncthreads();
    #pragma unroll
    for (int i = 0; i < 4; i++) {
        const int rr = r + i * 8;
        o[(long)(bj * 32 + rr) * EMB + bi * 32 + c] = f2bf(tile[c][rr]);
    }
}

// ---------------- fill cls + text rows of t (bf16) ----------------
__global__ __launch_bounds__(256)
void fill_rows_kernel(const float* __restrict__ cls, const float* __restrict__ text,
                      u16* __restrict__ t)
{
    const int b = blockIdx.y, r = blockIdx.x;
    const int tid = threadIdx.x;
    const long trow = (long)b * NTOK + (r == 0 ? 0 : NPATCH + r);
    const float* src = (r == 0) ? cls : text + ((long)b * NTEXT + (r - 1)) * EMB;
    u16* dst = t + trow * EMB;
    #pragma unroll
    for (int s = 0; s < 3; s++) dst[tid + s * 256] = f2bf(src[tid + s * 256]);
}

// ---------------- patch-embed MFMA GEMM (gathered fp32 A -> bf16), writes t ----------------
#define LDK 40   // 32 + 8 pad (80B rows: 16B-aligned)

__global__ __launch_bounds__(256)
void patch_mfma(const float* __restrict__ x, const u16* __restrict__ Bt,
                const float* __restrict__ bias, u16* __restrict__ t)
{
    __shared__ __align__(16) u16 As[128 * LDK];
    __shared__ __align__(16) u16 Bs[128 * LDK];
    const int m0 = blockIdx.y * 128, n0 = blockIdx.x * 128;
    const int tid = threadIdx.x;
    const int lane = tid & 63, w = tid >> 6, wr = w >> 1, wc = w & 1;
    const int l15 = lane & 15, g = lane >> 4;
    const int srow = tid >> 1, sseg = tid & 1;

    const int ar = m0 + srow;
    const int bb = ar / NPATCH, pidx = ar % NPATCH;
    const int hh = pidx / 24, wwp = pidx % 24;

    f32x4 acc[4][4] = {};

    for (int k0 = 0; k0 < EMB; k0 += 32) {
        {
            const int kb = k0 + sseg * 16;
            u32 wds[8];
            #pragma unroll
            for (int jj = 0; jj < 8; jj++) {
                float f[2];
                #pragma unroll
                for (int e = 0; e < 2; e++) {
                    const int kk = kb + jj * 2 + e;
                    const int cc = kk % 3, p12 = kk / 3, p1 = p12 >> 4, p2 = p12 & 15;
                    f[e] = x[((long)(bb * 3 + cc) * 384 + hh * 16 + p1) * 384 + wwp * 16 + p2];
                }
                wds[jj] = pk2(f[0], f[1]);
            }
            u32* dstp = (u32*)&As[srow * LDK + sseg * 16];
            *(uint4*)dstp = make_uint4(wds[0], wds[1], wds[2], wds[3]);
            *(uint4*)(dstp + 4) = make_uint4(wds[4], wds[5], wds[6], wds[7]);
        }
        {
            const u16* p = Bt + (long)(n0 + srow) * EMB + k0 + sseg * 16;
            u16* dstp = &Bs[srow * LDK + sseg * 16];
            *(uint4*)dstp = *(const uint4*)p;
            *(uint4*)(dstp + 8) = *(const uint4*)(p + 8);
        }
        __syncthreads();
        BF8 af[4], bfr[4];
        #pragma unroll
        for (int mi = 0; mi < 4; mi++)
            af[mi].u4 = *(const uint4*)&As[(wr * 64 + mi * 16 + l15) * LDK + g * 8];
        #pragma unroll
        for (int nj = 0; nj < 4; nj++)
            bfr[nj].u4 = *(const uint4*)&Bs[(wc * 64 + nj * 16 + l15) * LDK + g * 8];
        #pragma unroll
        for (int mi = 0; mi < 4; mi++)
            #pragma unroll
            for (int nj = 0; nj < 4; nj++)
                acc[mi][nj] = mfma16(af[mi].v, bfr[nj].v, acc[mi][nj]);
        __syncthreads();
    }
    float bv[4];
    #pragma unroll
    for (int nj = 0; nj < 4; nj++) bv[nj] = bias[n0 + wc * 64 + nj * 16 + l15];
    #pragma unroll
    for (int mi = 0; mi < 4; mi++) {
        #pragma unroll
        for (int rr = 0; rr < 4; rr++) {
            const int r = m0 + wr * 64 + mi * 16 + 4 * g + rr;
            const int b2 = r / NPATCH, pr = r % NPATCH;
            u16* cp = t + ((long)b2 * NTOK + 1 + pr) * EMB;
            #pragma unroll
            for (int nj = 0; nj < 4; nj++) {
                const int cc = n0 + wc * 64 + nj * 16 + l15;
                cp[cc] = f2bf(acc[mi][nj][rr] + bv[nj]);
            }
        }
    }
}

// ---------------- LN1: t(bf16) -> h(bf16) ----------------
__global__ __launch_bounds__(256)
void ln_h_kernel(const u16* __restrict__ t, u16* __restrict__ h,
                 const float* __restrict__ g, const float* __restrict__ be)
{
    __shared__ float red[256];
    const int row = blockIdx.x, tid = threadIdx.x;
    const u16* xp = t + (long)row * EMB;
    const float v0 = bf2f(xp[tid]), v1 = bf2f(xp[tid + 256]), v2 = bf2f(xp[tid + 512]);
    const float mu = blk_sum(v0 + v1 + v2, red, tid) * (1.f / EMB);
    const float d0 = v0 - mu, d1 = v1 - mu, d2 = v2 - mu;
    const float var = blk_sum(d0 * d0 + d1 * d1 + d2 * d2, red, tid) * (1.f / EMB);
    const float rs = rsqrtf(var + LN_EPS);
    u16* o = h + (long)row * EMB;
    o[tid]       = f2bf(d0 * rs * g[tid]       + be[tid]);
    o[tid + 256] = f2bf(d1 * rs * g[tid + 256] + be[tid + 256]);
    o[tid + 512] = f2bf(d2 * rs * g[tid + 512] + be[tid + 512]);
}

// ---------------- dense MFMA GEMM: C[M,768] = A(bf16) @ Wt^T + bias ----------------
template<bool OBF16>
__global__ __launch_bounds__(256)
void dense_gemm(const u16* __restrict__ A, const u16* __restrict__ Bt,
                const float* __restrict__ bias, void* __restrict__ Cout, int M)
{
    __shared__ __align__(16) u16 As[128 * LDK];
    __shared__ __align__(16) u16 Bs[128 * LDK];
    const int m0 = blockIdx.y * 128, n0 = blockIdx.x * 128;
    const int tid = threadIdx.x;
    const int lane = tid & 63, w = tid >> 6, wr = w >> 1, wc = w & 1;
    const int l15 = lane & 15, g = lane >> 4;
    const int srow = tid >> 1, sseg = tid & 1;
    const int ar = m0 + srow;

    f32x4 acc[4][4] = {};

    for (int k0 = 0; k0 < EMB; k0 += 32) {
        {
            u16* dstp = &As[srow * LDK + sseg * 16];
            if (ar < M) {
                const u16* p = A + (long)ar * EMB + k0 + sseg * 16;
                *(uint4*)dstp = *(const uint4*)p;
                *(uint4*)(dstp + 8) = *(const uint4*)(p + 8);
            } else {
                *(uint4*)dstp = make_uint4(0, 0, 0, 0);
                *(uint4*)(dstp + 8) = make_uint4(0, 0, 0, 0);
            }
        }
        {
            const u16* p = Bt + (long)(n0 + srow) * EMB + k0 + sseg * 16;
            u16* dstp = &Bs[srow * LDK + sseg * 16];
            *(uint4*)dstp = *(const uint4*)p;
            *(uint4*)(dstp + 8) = *(const uint4*)(p + 8);
        }
        __syncthreads();
        BF8 af[4], bfr[4];
        #pragma unroll
        for (int mi = 0; mi < 4; mi++)
            af[mi].u4 = *(const uint4*)&As[(wr * 64 + mi * 16 + l15) * LDK + g * 8];
        #pragma unroll
        for (int nj = 0; nj < 4; nj++)
            bfr[nj].u4 = *(const uint4*)&Bs[(wc * 64 + nj * 16 + l15) * LDK + g * 8];
        #pragma unroll
        for (int mi = 0; mi < 4; mi++)
            #pragma unroll
            for (int nj = 0; nj < 4; nj++)
                acc[mi][nj] = mfma16(af[mi].v, bfr[nj].v, acc[mi][nj]);
        __syncthreads();
    }
    float bv[4];
    #pragma unroll
    for (int nj = 0; nj < 4; nj++) bv[nj] = bias[n0 + wc * 64 + nj * 16 + l15];
    #pragma unroll
    for (int mi = 0; mi < 4; mi++) {
        #pragma unroll
        for (int rr = 0; rr < 4; rr++) {
            const int r = m0 + wr * 64 + mi * 16 + 4 * g + rr;
            if (r >= M) continue;
            #pragma unroll
            for (int nj = 0; nj < 4; nj++) {
                const int cc = n0 + wc * 64 + nj * 16 + l15;
                const float val = acc[mi][nj][rr] + bv[nj];
                if (OBF16) ((u16*)Cout)[(long)r * EMB + cc] = f2bf(val);
                else       ((float*)Cout)[(long)r * EMB + cc] = val;
            }
        }
    }
}

// ---------------- flash attention (MFMA, canonical layouts everywhere) ----------------
// Block: 256 thr = 4 waves; wave owns 16 q-rows (64 q/block). KV tiles of 32 keys.
// S^T = mfma(K, Q): lane holds S^T[key = kb*16 + 4g+rr][q = l15]  (g = lane>>4).
// P canonicalized via per-wave LDS roundtrip -> A-frag P[q=l15][key=g*8+j].
// V staged TRANSPOSED in LDS (Vt[dv][key]) -> B-frag is one aligned uint4 read.
#define KLD 392   // K tile row stride (u16)
#define VTLD 40   // Vt row stride (u16), 80 B rows (16B aligned)

__global__ __launch_bounds__(256)
void flash_mfma(const u16* __restrict__ q, const u16* __restrict__ k,
                const u16* __restrict__ v, u16* __restrict__ o)
{
    __shared__ __align__(16) u16 Ks[32 * KLD];       // 25088 B
    __shared__ __align__(16) u16 Vt[384 * VTLD];     // 30720 B
    __shared__ __align__(16) u16 Ps[4 * 16 * VTLD];  // 5120 B (per-wave 16x40)

    const int bh = blockIdx.y, b = bh >> 1, h = bh & 1;
    const int q0 = blockIdx.x * 64;
    const int tid = threadIdx.x;
    const int lane = tid & 63, w = tid >> 6;
    const int l15 = lane & 15, g = lane >> 4;
    const long base = (long)b * NTOK * EMB + h * HD;

    // Q fragments in registers: 12 d-steps of 32
    BF8 qf[12];
    {
        const int qrow = q0 + w * 16 + l15;
        if (qrow < NTOK) {
            const u16* src = q + base + (long)qrow * EMB;
            #pragma unroll
            for (int ds = 0; ds < 12; ds++)
                qf[ds].u4 = *(const uint4*)(src + ds * 32 + g * 8);
        } else {
            #pragma unroll
            for (int ds = 0; ds < 12; ds++) qf[ds].u4 = make_uint4(0, 0, 0, 0);
        }
    }

    float m_run = -3.0e38f, l_run = 0.f;
    f32x4 oacc[24] = {};

    const int skey = tid >> 3, sseg = tid & 7;   // K staging mapping

    for (int kt = 0; kt < 21; kt++) {
        const int kv0 = kt * 32;
        __syncthreads();  // protect Ks/Vt from previous iteration's readers

        // ---- stage K tile [32][KLD] ----
        {
            const int kr = kv0 + skey;
            u16* dstp = &Ks[skey * KLD + sseg * 48];
            if (kr < NTOK) {
                const u16* ks = k + base + (long)kr * EMB + sseg * 48;
                #pragma unroll
                for (int i = 0; i < 6; i++)
                    *(uint4*)(dstp + i * 8) = *(const uint4*)(ks + i * 8);
            } else {
                #pragma unroll
                for (int i = 0; i < 6; i++) *(uint4*)(dstp + i * 8) = make_uint4(0, 0, 0, 0);
            }
        }
        // ---- stage V transposed: Vt[dv][key] (768 tasks: kp=task&15, dseg=task>>4) ----
        #pragma unroll
        for (int tt = 0; tt < 3; tt++) {
            const int task = tid + tt * 256;
            const int kp = task & 15, dseg = task >> 4;
            const int kr0 = kv0 + 2 * kp;
            uint4 va = make_uint4(0, 0, 0, 0), vb4 = make_uint4(0, 0, 0, 0);
            if (kr0 < NTOK)     va  = *(const uint4*)(v + base + (long)kr0 * EMB + dseg * 8);
            if (kr0 + 1 < NTOK) vb4 = *(const uint4*)(v + base + (long)(kr0 + 1) * EMB + dseg * 8);
            const u16* ae = (const u16*)&va;
            const u16* be = (const u16*)&vb4;
            #pragma unroll
            for (int e = 0; e < 8; e++)
                *(u32*)&Vt[(dseg * 8 + e) * VTLD + 2 * kp] =
                    (u32)ae[e] | ((u32)be[e] << 16);
        }
        __syncthreads();

        // ---- S^T = K @ Q^T ----
        f32x4 sacc[2] = {};
        #pragma unroll
        for (int ds = 0; ds < 12; ds++) {
            BF8 ak0, ak1;
            ak0.u4 = *(const uint4*)&Ks[(l15) * KLD + ds * 32 + g * 8];
            ak1.u4 = *(const uint4*)&Ks[(16 + l15) * KLD + ds * 32 + g * 8];
            sacc[0] = mfma16(ak0.v, qf[ds].v, sacc[0]);
            sacc[1] = mfma16(ak1.v, qf[ds].v, sacc[1]);
        }

        // ---- mask + online softmax (per q = l15) ----
        float pe[2][4];
        float mx = -3.0e38f;
        #pragma unroll
        for (int kb = 0; kb < 2; kb++)
            #pragma unroll
            for (int rr = 0; rr < 4; rr++) {
                float s = sacc[kb][rr];
                if (kv0 + kb * 16 + 4 * g + rr >= NTOK) s = -1e30f;
                pe[kb][rr] = s;
                mx = fmaxf(mx, s);
            }
        mx = fmaxf(mx, __shfl_xor(mx, 16, 64));
        mx = fmaxf(mx, __shfl_xor(mx, 32, 64));
        const float m_new = fmaxf(m_run, mx);
        const float corr = __expf(m_run - m_new);
        float psum = 0.f;
        #pragma unroll
        for (int kb = 0; kb < 2; kb++)
            #pragma unroll
            for (int rr = 0; rr < 4; rr++) {
                pe[kb][rr] = __expf(pe[kb][rr] - m_new);
                psum += pe[kb][rr];
            }
        psum += __shfl_xor(psum, 16, 64);
        psum += __shfl_xor(psum, 32, 64);
        l_run = l_run * corr + psum;
        m_run = m_new;

        // ---- canonicalize P via per-wave LDS roundtrip ----
        // lane (q=l15, g) holds keys {4g+rr} and {16+4g+rr}; write Ps[q][key] packed.
        {
            char* prow = (char*)Ps + w * (16 * VTLD * 2) + l15 * (VTLD * 2);
            u32* pw = (u32*)prow;
            pw[g * 2]         = pk2(pe[0][0], pe[0][1]);   // keys 4g, 4g+1
            pw[g * 2 + 1]     = pk2(pe[0][2], pe[0][3]);   // keys 4g+2, 4g+3
            pw[8 + g * 2]     = pk2(pe[1][0], pe[1][1]);   // keys 16+4g, 16+4g+1
            pw[8 + g * 2 + 1] = pk2(pe[1][2], pe[1][3]);   // keys 16+4g+2, 16+4g+3
        }
        asm volatile("s_waitcnt lgkmcnt(0)" ::: "memory");
        __builtin_amdgcn_sched_barrier(0);
        BF8 pa;
        pa.u4 = *(const uint4*)((char*)Ps + w * (16 * VTLD * 2) + l15 * (VTLD * 2) + g * 16);

        // corr broadcast to O-frag rows (lane's oacc rows are q = 4g+rr)
        float cb[4];
        #pragma unroll
        for (int rr = 0; rr < 4; rr++) cb[rr] = __shfl(corr, 4 * g + rr, 64);

        // ---- PV: O[q][dv] += P @ V, B-frag from Vt (canonical B^T read) ----
        #pragma unroll
        for (int dc = 0; dc < 24; dc++) {
            #pragma unroll
            for (int rr = 0; rr < 4; rr++) oacc[dc][rr] *= cb[rr];
            BF8 vb;
            vb.u4 = *(const uint4*)&Vt[(dc * 16 + l15) * VTLD + g * 8];
            oacc[dc] = mfma16(pa.v, vb.v, oacc[dc]);
        }
    }

    // ---- store O (scaled by 1/(l*sqrt(768))) ----
    float linv[4];
    #pragma unroll
    for (int rr = 0; rr < 4; rr++)
        linv[rr] = INV_SQRT_EMB / __shfl(l_run, 4 * g + rr, 64);
    #pragma unroll
    for (int rr = 0; rr < 4; rr++) {
        const int row = q0 + w * 16 + 4 * g + rr;
        if (row < NTOK) {
            u16* dst = o + base + (long)row * EMB;
            #pragma unroll
            for (int dc = 0; dc < 24; dc++)
                dst[dc * 16 + l15] = f2bf(oacc[dc][rr] * linv[rr]);
        }
    }
}

// ---------------- LN2 then residual-add into t (bf16) ----------------
__global__ __launch_bounds__(256)
void ln_add_kernel(const float* __restrict__ in, u16* __restrict__ t,
                   const float* __restrict__ g, const float* __restrict__ be)
{
    __shared__ float red[256];
    const int row = blockIdx.x, tid = threadIdx.x;
    const float* x = in + (long)row * EMB;
    const float v0 = x[tid], v1 = x[tid + 256], v2 = x[tid + 512];
    const float mu = blk_sum(v0 + v1 + v2, red, tid) * (1.f / EMB);
    const float d0 = v0 - mu, d1 = v1 - mu, d2 = v2 - mu;
    const float var = blk_sum(d0 * d0 + d1 * d1 + d2 * d2, red, tid) * (1.f / EMB);
    const float rs = rsqrtf(var + LN_EPS);
    u16* o = t + (long)row * EMB;
    o[tid]       = f2bf(bf2f(o[tid])       + d0 * rs * g[tid]       + be[tid]);
    o[tid + 256] = f2bf(bf2f(o[tid + 256]) + d1 * rs * g[tid + 256] + be[tid + 256]);
    o[tid + 512] = f2bf(bf2f(o[tid + 512]) + d2 * rs * g[tid + 512] + be[tid + 512]);
}

// ---------------- mean over tokens ----------------
__global__ __launch_bounds__(128)
void meanpool_kernel(const u16* __restrict__ t, float* __restrict__ m)
{
    const int b = blockIdx.y;
    const int e = blockIdx.x * 128 + threadIdx.x;
    const u16* p = t + (long)b * NTOK * EMB + e;
    float s = 0.f;
    for (int j = 0; j < NTOK; j++) s += bf2f(p[(long)j * EMB]);
    m[b * EMB + e] = s * (1.f / NTOK);
}

// ---------------- LN3 + final Linear (fp32) ----------------
__global__ __launch_bounds__(256)
void final_kernel(const float* __restrict__ m, const float* __restrict__ g,
                  const float* __restrict__ be, const float* __restrict__ Wf,
                  const float* __restrict__ bf, float* __restrict__ out)
{
    __shared__ float red[256];
    __shared__ float mln[EMB];
    const int b = blockIdx.x, tid = threadIdx.x;
    const float* x = m + b * EMB;
    const float v0 = x[tid], v1 = x[tid + 256], v2 = x[tid + 512];
    const float mu = blk_sum(v0 + v1 + v2, red, tid) * (1.f / EMB);
    const float d0 = v0 - mu, d1 = v1 - mu, d2 = v2 - mu;
    const float var = blk_sum(d0 * d0 + d1 * d1 + d2 * d2, red, tid) * (1.f / EMB);
    const float rs = rsqrtf(var + LN_EPS);
    mln[tid]       = d0 * rs * g[tid]       + be[tid];
    mln[tid + 256] = d1 * rs * g[tid + 256] + be[tid + 256];
    mln[tid + 512] = d2 * rs * g[tid + 512] + be[tid + 512];
    __syncthreads();
    #pragma unroll
    for (int s = 0; s < 3; s++) {
        const int e = tid + s * 256;
        float acc = bf[e];
        #pragma unroll 8
        for (int kk = 0; kk < EMB; kk++) acc += mln[kk] * Wf[(long)kk * EMB + e];
        out[(long)b * EMB + e] = acc;
    }
}

extern "C" void kernel_launch(void* const* d_in, const int* in_sizes, int n_in,
                              void* d_out, int out_size, void* d_ws, size_t ws_size,
                              hipStream_t stream) {
    const float* x      = (const float*)d_in[0];
    const float* text   = (const float*)d_in[1];
    const float* Wpatch = (const float*)d_in[2];
    const float* bpatch = (const float*)d_in[3];
    const float* cls    = (const float*)d_in[4];
    const float* g1  = (const float*)d_in[5];
    const float* be1 = (const float*)d_in[6];
    const float* Wq  = (const float*)d_in[7];
    const float* bq  = (const float*)d_in[8];
    const float* Wk  = (const float*)d_in[9];
    const float* bk  = (const float*)d_in[10];
    const float* Wv  = (const float*)d_in[11];
    const float* bv  = (const float*)d_in[12];
    const float* Wp  = (const float*)d_in[13];
    const float* bp  = (const float*)d_in[14];
    const float* g2  = (const float*)d_in[15];
    const float* be2 = (const float*)d_in[16];
    const float* g3  = (const float*)d_in[17];
    const float* be3 = (const float*)d_in[18];
    const float* Wf  = (const float*)d_in[19];
    const float* bf  = (const float*)d_in[20];

    // ws layout (~167 MB):
    //  t bf16 | h bf16 | q bf16 | k bf16 | v bf16  (5 x 32.1 MB)
    //  o2 fp32 (64.3 MB) overlaps k+v (dead after flash)
    //  Wt bf16 (5 x 1.18 MB) | mp fp32
    char* ws = (char*)d_ws;
    const size_t S2 = (size_t)MROWS * EMB * 2;   // 32,145,408
    u16*   t   = (u16*)ws;
    u16*   hb  = (u16*)(ws + S2);
    u16*   qb  = (u16*)(ws + 2 * S2);
    u16*   kbf = (u16*)(ws + 3 * S2);
    u16*   vbf = (u16*)(ws + 4 * S2);
    float* o2  = (float*)(ws + 3 * S2);
    u16*   wt  = (u16*)(ws + 5 * S2);
    float* mp  = (float*)(ws + 5 * S2 + (size_t)5 * EMB * EMB * 2);
    const size_t WTS = (size_t)EMB * EMB;

    // 1) weights -> bf16 transposed
    wt_kernel<<<dim3(24, 24, 5), 256, 0, stream>>>(Wpatch, Wq, Wk, Wv, Wp, wt);
    // 2) cls + text rows of t
    fill_rows_kernel<<<dim3(NTEXT + 1, NBATCH), 256, 0, stream>>>(cls, text, t);
    // 3) patch embed -> t
    patch_mfma<<<dim3(6, NBATCH * NPATCH / 128), 256, 0, stream>>>(x, wt, bpatch, t);
    // 4) h = LN1(t) bf16
    ln_h_kernel<<<MROWS, 256, 0, stream>>>(t, hb, g1, be1);
    // 5) QKV
    const dim3 gQ(6, (MROWS + 127) / 128);
    dense_gemm<true><<<gQ, 256, 0, stream>>>(hb, wt + 1 * WTS, bq, qb,  MROWS);
    dense_gemm<true><<<gQ, 256, 0, stream>>>(hb, wt + 2 * WTS, bk, kbf, MROWS);
    dense_gemm<true><<<gQ, 256, 0, stream>>>(hb, wt + 3 * WTS, bv, vbf, MROWS);
    // 6) flash attention (o over q)
    flash_mfma<<<dim3(11, NBATCH * 2), 256, 0, stream>>>(qb, kbf, vbf, qb);
    // 7) proj -> o2 fp32
    dense_gemm<false><<<gQ, 256, 0, stream>>>(qb, wt + 4 * WTS, bp, o2, MROWS);
    // 8) t += LN2(o2)
    ln_add_kernel<<<MROWS, 256, 0, stream>>>(o2, t, g2, be2);
    // 9) mean pool
    meanpool_kernel<<<dim3(6, NBATCH), 128, 0, stream>>>(t, mp);
    // 10) LN3 + final linear
    final_kernel<<<NBATCH, 256, 0, stream>>>(mp, g3, be3, Wf, bf, (float*)d_out);
}

// Round 5
// 764.056 us; speedup vs baseline: 4.2312x; 1.1927x over previous
//
#include <hip/hip_runtime.h>
#include <hip/hip_bf16.h>
#include <math.h>

#define EMB 768
#define NTOK 654
#define NPATCH 576
#define NTEXT 77
#define NBATCH 32
#define HD 384
#define MROWS (NBATCH * NTOK)   // 20928
#define LN_EPS 1e-5f
#define INV_SQRT_EMB 0.03608439182435161f

typedef unsigned int u32;
typedef unsigned short u16;
typedef float f32x4 __attribute__((ext_vector_type(4)));
typedef __bf16 bf16x8 __attribute__((ext_vector_type(8)));

union BF8 { uint4 u4; u32 w[4]; bf16x8 v; };

// async global->LDS, 16B per lane; dest = wave-uniform base + lane*16
#define GLL(gsrc, ldst) __builtin_amdgcn_global_load_lds( \
    (const __attribute__((address_space(1))) unsigned int*)(gsrc), \
    (__attribute__((address_space(3))) unsigned int*)(ldst), 16, 0, 0)

// ---------------- helpers ----------------
__device__ __forceinline__ float bf2f(u16 u) {
    union { u32 i; float f; } x; x.i = ((u32)u) << 16; return x.f;
}
__device__ __forceinline__ u16 f2bf(float f) {  // RTNE
    union { float f; u32 i; } x; x.f = f;
    u32 r = x.i + 0x7fffu + ((x.i >> 16) & 1u);
    return (u16)(r >> 16);
}
__device__ __forceinline__ u32 pk2(float lo, float hi) {
    return (u32)f2bf(lo) | ((u32)f2bf(hi) << 16);
}
__device__ __forceinline__ float blk_sum(float v, float* red, int tid) {
    red[tid] = v; __syncthreads();
    #pragma unroll
    for (int s = 128; s > 0; s >>= 1) {
        if (tid < s) red[tid] += red[tid + s];
        __syncthreads();
    }
    float r = red[0]; __syncthreads();
    return r;
}
__device__ __forceinline__ f32x4 mfma16(bf16x8 a, bf16x8 b, f32x4 c) {
    return __builtin_amdgcn_mfma_f32_16x16x32_bf16(a, b, c, 0, 0, 0);
}

// ---------------- weight transpose + bf16: Wt[n][k] = bf16(W[k][n]) ----------------
__global__ __launch_bounds__(256)
void wt_kernel(const float* __restrict__ W0, const float* __restrict__ W1,
               const float* __restrict__ W2, const float* __restrict__ W3,
               const float* __restrict__ W4, u16* __restrict__ dst)
{
    __shared__ float tile[32][33];
    const int z = blockIdx.z;
    const float* W = (z == 0) ? W0 : (z == 1) ? W1 : (z == 2) ? W2 : (z == 3) ? W3 : W4;
    u16* o = dst + (size_t)z * EMB * EMB;
    const int bi = blockIdx.y, bj = blockIdx.x;
    const int r = threadIdx.x >> 5, c = threadIdx.x & 31;
    #pragma unroll
    for (int i = 0; i < 4; i++)
        tile[r + i * 8][c] = W[(long)(bi * 32 + r + i * 8) * EMB + bj * 32 + c];
    __syncthreads();
    #pragma unroll
    for (int i = 0; i < 4; i++) {
        const int rr = r + i * 8;
        o[(long)(bj * 32 + rr) * EMB + bi * 32 + c] = f2bf(tile[c][rr]);
    }
}

// ---------------- fill cls + text rows of t (bf16) ----------------
__global__ __launch_bounds__(256)
void fill_rows_kernel(const float* __restrict__ cls, const float* __restrict__ text,
                      u16* __restrict__ t)
{
    const int b = blockIdx.y, r = blockIdx.x;
    const int tid = threadIdx.x;
    const long trow = (long)b * NTOK + (r == 0 ? 0 : NPATCH + r);
    const float* src = (r == 0) ? cls : text + ((long)b * NTEXT + (r - 1)) * EMB;
    u16* dst = t + trow * EMB;
    #pragma unroll
    for (int s = 0; s < 3; s++) dst[tid + s * 256] = f2bf(src[tid + s * 256]);
}

// ---------------- patch-embed MFMA GEMM (gathered fp32 A -> bf16), writes t ----------------
#define LDK 40   // 32 + 8 pad (80B rows: 16B-aligned)

__global__ __launch_bounds__(256)
void patch_mfma(const float* __restrict__ x, const u16* __restrict__ Bt,
                const float* __restrict__ bias, u16* __restrict__ t)
{
    __shared__ __align__(16) u16 As[128 * LDK];
    __shared__ __align__(16) u16 Bs[128 * LDK];
    const int m0 = blockIdx.y * 128, n0 = blockIdx.x * 128;
    const int tid = threadIdx.x;
    const int lane = tid & 63, w = tid >> 6, wr = w >> 1, wc = w & 1;
    const int l15 = lane & 15, g = lane >> 4;
    const int srow = tid >> 1, sseg = tid & 1;

    const int ar = m0 + srow;
    const int bb = ar / NPATCH, pidx = ar % NPATCH;
    const int hh = pidx / 24, wwp = pidx % 24;

    f32x4 acc[4][4] = {};

    for (int k0 = 0; k0 < EMB; k0 += 32) {
        {
            const int kb = k0 + sseg * 16;
            u32 wds[8];
            #pragma unroll
            for (int jj = 0; jj < 8; jj++) {
                float f[2];
                #pragma unroll
                for (int e = 0; e < 2; e++) {
                    const int kk = kb + jj * 2 + e;
                    const int cc = kk % 3, p12 = kk / 3, p1 = p12 >> 4, p2 = p12 & 15;
                    f[e] = x[((long)(bb * 3 + cc) * 384 + hh * 16 + p1) * 384 + wwp * 16 + p2];
                }
                wds[jj] = pk2(f[0], f[1]);
            }
            u32* dstp = (u32*)&As[srow * LDK + sseg * 16];
            *(uint4*)dstp = make_uint4(wds[0], wds[1], wds[2], wds[3]);
            *(uint4*)(dstp + 4) = make_uint4(wds[4], wds[5], wds[6], wds[7]);
        }
        {
            const u16* p = Bt + (long)(n0 + srow) * EMB + k0 + sseg * 16;
            u16* dstp = &Bs[srow * LDK + sseg * 16];
            *(uint4*)dstp = *(const uint4*)p;
            *(uint4*)(dstp + 8) = *(const uint4*)(p + 8);
        }
        __syncthreads();
        BF8 af[4], bfr[4];
        #pragma unroll
        for (int mi = 0; mi < 4; mi++)
            af[mi].u4 = *(const uint4*)&As[(wr * 64 + mi * 16 + l15) * LDK + g * 8];
        #pragma unroll
        for (int nj = 0; nj < 4; nj++)
            bfr[nj].u4 = *(const uint4*)&Bs[(wc * 64 + nj * 16 + l15) * LDK + g * 8];
        #pragma unroll
        for (int mi = 0; mi < 4; mi++)
            #pragma unroll
            for (int nj = 0; nj < 4; nj++)
                acc[mi][nj] = mfma16(af[mi].v, bfr[nj].v, acc[mi][nj]);
        __syncthreads();
    }
    float bv[4];
    #pragma unroll
    for (int nj = 0; nj < 4; nj++) bv[nj] = bias[n0 + wc * 64 + nj * 16 + l15];
    #pragma unroll
    for (int mi = 0; mi < 4; mi++) {
        #pragma unroll
        for (int rr = 0; rr < 4; rr++) {
            const int r = m0 + wr * 64 + mi * 16 + 4 * g + rr;
            const int b2 = r / NPATCH, pr = r % NPATCH;
            u16* cp = t + ((long)b2 * NTOK + 1 + pr) * EMB;
            #pragma unroll
            for (int nj = 0; nj < 4; nj++) {
                const int cc = n0 + wc * 64 + nj * 16 + l15;
                cp[cc] = f2bf(acc[mi][nj][rr] + bv[nj]);
            }
        }
    }
}

// ---------------- LN1: t(bf16) -> h(bf16) ----------------
__global__ __launch_bounds__(256)
void ln_h_kernel(const u16* __restrict__ t, u16* __restrict__ h,
                 const float* __restrict__ g, const float* __restrict__ be)
{
    __shared__ float red[256];
    const int row = blockIdx.x, tid = threadIdx.x;
    const u16* xp = t + (long)row * EMB;
    const float v0 = bf2f(xp[tid]), v1 = bf2f(xp[tid + 256]), v2 = bf2f(xp[tid + 512]);
    const float mu = blk_sum(v0 + v1 + v2, red, tid) * (1.f / EMB);
    const float d0 = v0 - mu, d1 = v1 - mu, d2 = v2 - mu;
    const float var = blk_sum(d0 * d0 + d1 * d1 + d2 * d2, red, tid) * (1.f / EMB);
    const float rs = rsqrtf(var + LN_EPS);
    u16* o = h + (long)row * EMB;
    o[tid]       = f2bf(d0 * rs * g[tid]       + be[tid]);
    o[tid + 256] = f2bf(d1 * rs * g[tid + 256] + be[tid + 256]);
    o[tid + 512] = f2bf(d2 * rs * g[tid + 512] + be[tid + 512]);
}

// ---------------- dense MFMA GEMM v2: global_load_lds + dbuf + counted vmcnt ----------
// C[M,768] = A(bf16) @ Wt^T + bias. BK=64, linear LDS [128][64]u16, granule-XOR swizzle
// (slot s holds global granule s^(r&7)); 2-phase pipeline, vmcnt(8) counted.
#define DBK 64
#define DTILE_B (128 * DBK * 2)   // 16384 B per tile

template<bool OBF16>
__global__ __launch_bounds__(256)
void dense_gemm(const u16* __restrict__ A, const u16* __restrict__ Bt,
                const float* __restrict__ bias, void* __restrict__ Cout, int M)
{
    extern __shared__ char sm[];   // [2][A|B][128][64]u16 = 65536 B
    const int wgid = blockIdx.x;   // 984 blocks = 8 * 123
    const int work = (wgid & 7) * 123 + (wgid >> 3);
    const int n0 = (work % 6) * 128, m0 = (work / 6) * 128;
    const int tid = threadIdx.x;
    const int lane = tid & 63, w = tid >> 6, wr = w >> 1, wc = w & 1;
    const int l15 = lane & 15, g = lane >> 4;
    const int wbase = (tid & ~63);

    f32x4 acc[4][4] = {};

    // stage tile k0 into buffer buf (8 global_load_lds per thread)
    auto stage = [&](int k0, int buf) {
        char* dst = sm + buf * 2 * DTILE_B;
        #pragma unroll
        for (int c = 0; c < 4; c++) {
            const int idx = c * 256 + tid;
            const int r = idx >> 3, s = idx & 7;
            const int gs = s ^ (r & 7);
            const int ar = min(m0 + r, M - 1);
            GLL(A + (long)ar * EMB + k0 + gs * 8, dst + (c * 256 + wbase) * 16);
        }
        #pragma unroll
        for (int c = 0; c < 4; c++) {
            const int idx = c * 256 + tid;
            const int r = idx >> 3, s = idx & 7;
            const int gs = s ^ (r & 7);
            GLL(Bt + (long)(n0 + r) * EMB + k0 + gs * 8,
                dst + DTILE_B + (c * 256 + wbase) * 16);
        }
    };

    stage(0, 0);
    for (int t = 0; t < 12; t++) {
        if (t < 11) {
            stage((t + 1) * DBK, (t + 1) & 1);
            asm volatile("s_waitcnt vmcnt(8)" ::: "memory");   // tile t landed, t+1 in flight
        } else {
            asm volatile("s_waitcnt vmcnt(0)" ::: "memory");
        }
        __syncthreads();
        const char* Asb = sm + (t & 1) * 2 * DTILE_B;
        const char* Bsb = Asb + DTILE_B;
        #pragma unroll
        for (int ks = 0; ks < 2; ks++) {
            BF8 af[4], bfr[4];
            #pragma unroll
            for (int mi = 0; mi < 4; mi++) {
                const int row = wr * 64 + mi * 16 + l15;
                const int slot = (ks * 4 + g) ^ (row & 7);
                af[mi].u4 = *(const uint4*)(Asb + row * 128 + slot * 16);
            }
            #pragma unroll
            for (int nj = 0; nj < 4; nj++) {
                const int row = wc * 64 + nj * 16 + l15;
                const int slot = (ks * 4 + g) ^ (row & 7);
                bfr[nj].u4 = *(const uint4*)(Bsb + row * 128 + slot * 16);
            }
            #pragma unroll
            for (int mi = 0; mi < 4; mi++)
                #pragma unroll
                for (int nj = 0; nj < 4; nj++)
                    acc[mi][nj] = mfma16(af[mi].v, bfr[nj].v, acc[mi][nj]);
        }
        __syncthreads();
    }
    float bv[4];
    #pragma unroll
    for (int nj = 0; nj < 4; nj++) bv[nj] = bias[n0 + wc * 64 + nj * 16 + l15];
    #pragma unroll
    for (int mi = 0; mi < 4; mi++) {
        #pragma unroll
        for (int rr = 0; rr < 4; rr++) {
            const int r = m0 + wr * 64 + mi * 16 + 4 * g + rr;
            if (r >= M) continue;
            #pragma unroll
            for (int nj = 0; nj < 4; nj++) {
                const int cc = n0 + wc * 64 + nj * 16 + l15;
                const float val = acc[mi][nj][rr] + bv[nj];
                if (OBF16) ((u16*)Cout)[(long)r * EMB + cc] = f2bf(val);
                else       ((float*)Cout)[(long)r * EMB + cc] = val;
            }
        }
    }
}

// ---------------- flash attention v3 (MFMA + async K staging + V reg-prefetch) -------
// K: global_load_lds, linear [2][32][384]u16 double-buffer, granule-XOR swizzle.
// V: prefetched to regs (T14), ds_written transposed (Vt[384][36], conflict-free).
// S^T = mfma(K, Q); softmax lane-local + 2 shfl; P canonicalized via Ps roundtrip.
#define KS_TILE_B 24576   // 32*384*2
#define VTLD 36           // Vt row stride (u16), 72 B rows (b64-aligned reads)
#define PSLD 40           // Ps row stride (u16), 80 B rows (b128-aligned)
#define FLASH_LDS (2 * KS_TILE_B + 384 * VTLD * 2 + 4 * 16 * PSLD * 2)  // 81920

__global__ __launch_bounds__(256)
void flash_mfma(const u16* __restrict__ q, const u16* __restrict__ k,
                const u16* __restrict__ v, u16* __restrict__ o)
{
    extern __shared__ char smem[];
    char* KsB = smem;                                   // [2][32][384] u16
    u16* Vt = (u16*)(smem + 2 * KS_TILE_B);             // [384][VTLD]
    char* Ps = smem + 2 * KS_TILE_B + 384 * VTLD * 2;   // 4 waves x [16][PSLD]

    // XCD-bijective swizzle: 704 = 8 * 88, 88 = 8 bh-groups of 11 blocks per XCD
    const int wg = blockIdx.x;
    const int work = (wg & 7) * 88 + (wg >> 3);
    const int bh = work / 11, qblk = work % 11;
    const int b = bh >> 1, h = bh & 1;
    const int q0 = qblk * 64;
    const int tid = threadIdx.x;
    const int lane = tid & 63, w = tid >> 6;
    const int l15 = lane & 15, g = lane >> 4;
    const int wbase = (tid & ~63);
    const long base = (long)b * NTOK * EMB + h * HD;

    // Q fragments in registers: 12 d-steps of 32
    BF8 qf[12];
    {
        const int qrow = q0 + w * 16 + l15;
        if (qrow < NTOK) {
            const u16* src = q + base + (long)qrow * EMB;
            #pragma unroll
            for (int ds = 0; ds < 12; ds++)
                qf[ds].u4 = *(const uint4*)(src + ds * 32 + g * 8);
        } else {
            #pragma unroll
            for (int ds = 0; ds < 12; ds++) qf[ds].u4 = make_uint4(0, 0, 0, 0);
        }
    }

    // K async stage (6 x global_load_lds; addr-clamped, garbage rows masked later)
    auto stage_K = [&](int kv0, int buf) {
        #pragma unroll
        for (int c = 0; c < 6; c++) {
            const int idx = c * 256 + tid;
            const int r = idx / 48, gr = idx % 48;
            const int gsrc = (gr & ~7) | ((gr & 7) ^ (r & 7));
            const int kr = min(kv0 + r, NTOK - 1);
            GLL(k + base + (long)kr * EMB + gsrc * 8,
                KsB + buf * KS_TILE_B + (c * 256 + wbase) * 16);
        }
    };

    // V prefetch to regs (2 keys x 24 dv granules -> 6 uint4)
    const int kp = tid & 15;
    uint4 va[3], vb[3];
    auto load_V = [&](int kv0) {
        const int kr0 = kv0 + 2 * kp;
        const u16* v0p = v + base + (long)min(kr0, NTOK - 1) * EMB;
        const u16* v1p = v + base + (long)min(kr0 + 1, NTOK - 1) * EMB;
        #pragma unroll
        for (int tt = 0; tt < 3; tt++) {
            const int dseg = (tid >> 4) + tt * 16;
            va[tt] = *(const uint4*)(v0p + dseg * 8);
            vb[tt] = *(const uint4*)(v1p + dseg * 8);
        }
    };
    auto write_V = [&](int kv0) {
        const int kr0 = kv0 + 2 * kp;
        const bool ok0 = kr0 < NTOK, ok1 = (kr0 + 1) < NTOK;
        #pragma unroll
        for (int tt = 0; tt < 3; tt++) {
            const int dseg = (tid >> 4) + tt * 16;
            const u16* ae = (const u16*)&va[tt];
            const u16* be = (const u16*)&vb[tt];
            #pragma unroll
            for (int e = 0; e < 8; e++) {
                const u32 lo = ok0 ? (u32)ae[e] : 0u;
                const u32 hi = ok1 ? (u32)be[e] : 0u;
                *(u32*)&Vt[(dseg * 8 + e) * VTLD + 2 * kp] = lo | (hi << 16);
            }
        }
    };

    float m_run = -3.0e38f, l_run = 0.f;
    f32x4 oacc[24] = {};

    stage_K(0, 0);
    load_V(0);

    for (int kt = 0; kt < 21; kt++) {
        const int kv0 = kt * 32;
        asm volatile("s_waitcnt vmcnt(0)" ::: "memory");  // K(kt) in LDS, V(kt) in regs
        __syncthreads();                                   // prev PV done; all K(kt) visible
        write_V(kv0);
        if (kt < 20) { stage_K(kv0 + 32, (kt + 1) & 1); load_V(kv0 + 32); }
        __syncthreads();                                   // Vt(kt) visible

        // ---- S^T = K @ Q^T (swizzled reads) ----
        const char* kbuf = KsB + (kt & 1) * KS_TILE_B;
        f32x4 sacc[2] = {};
        __builtin_amdgcn_s_setprio(1);
        #pragma unroll
        for (int ds = 0; ds < 12; ds++) {
            const int idx = ds * 4 + g;
            const int slot = (idx & ~7) | ((idx & 7) ^ (l15 & 7));
            BF8 ak0, ak1;
            ak0.u4 = *(const uint4*)(kbuf + l15 * 768 + slot * 16);
            ak1.u4 = *(const uint4*)(kbuf + (16 + l15) * 768 + slot * 16);
            sacc[0] = mfma16(ak0.v, qf[ds].v, sacc[0]);
            sacc[1] = mfma16(ak1.v, qf[ds].v, sacc[1]);
        }
        __builtin_amdgcn_s_setprio(0);

        // ---- mask + online softmax (per q = l15) ----
        float pe[2][4];
        float mx = -3.0e38f;
        #pragma unroll
        for (int kb = 0; kb < 2; kb++)
            #pragma unroll
            for (int rr = 0; rr < 4; rr++) {
                float s = sacc[kb][rr];
                if (kv0 + kb * 16 + 4 * g + rr >= NTOK) s = -1e30f;
                pe[kb][rr] = s;
                mx = fmaxf(mx, s);
            }
        mx = fmaxf(mx, __shfl_xor(mx, 16, 64));
        mx = fmaxf(mx, __shfl_xor(mx, 32, 64));
        const float m_new = fmaxf(m_run, mx);
        const float corr = __expf(m_run - m_new);
        float psum = 0.f;
        #pragma unroll
        for (int kb = 0; kb < 2; kb++)
            #pragma unroll
            for (int rr = 0; rr < 4; rr++) {
                pe[kb][rr] = __expf(pe[kb][rr] - m_new);
                psum += pe[kb][rr];
            }
        psum += __shfl_xor(psum, 16, 64);
        psum += __shfl_xor(psum, 32, 64);
        l_run = l_run * corr + psum;
        m_run = m_new;

        // ---- canonicalize P via per-wave LDS roundtrip (Ps[q][key], stride PSLD) ----
        {
            u32* pw = (u32*)(Ps + w * (16 * PSLD * 2) + l15 * (PSLD * 2));
            pw[g * 2]         = pk2(pe[0][0], pe[0][1]);
            pw[g * 2 + 1]     = pk2(pe[0][2], pe[0][3]);
            pw[8 + g * 2]     = pk2(pe[1][0], pe[1][1]);
            pw[8 + g * 2 + 1] = pk2(pe[1][2], pe[1][3]);
        }
        asm volatile("s_waitcnt lgkmcnt(0)" ::: "memory");
        __builtin_amdgcn_sched_barrier(0);
        BF8 pa;
        pa.u4 = *(const uint4*)(Ps + w * (16 * PSLD * 2) + l15 * (PSLD * 2) + g * 16);

        float cb[4];
        #pragma unroll
        for (int rr = 0; rr < 4; rr++) cb[rr] = __shfl(corr, 4 * g + rr, 64);

        // ---- PV: O[q][dv] += P @ V (Vt b64-pair reads, conflict-free) ----
        __builtin_amdgcn_s_setprio(1);
        #pragma unroll
        for (int dc = 0; dc < 24; dc++) {
            #pragma unroll
            for (int rr = 0; rr < 4; rr++) oacc[dc][rr] *= cb[rr];
            const u16* vp = &Vt[(dc * 16 + l15) * VTLD + g * 8];
            const uint2 lo = *(const uint2*)vp;
            const uint2 hi = *(const uint2*)(vp + 4);
            BF8 vb8;
            vb8.w[0] = lo.x; vb8.w[1] = lo.y; vb8.w[2] = hi.x; vb8.w[3] = hi.y;
            oacc[dc] = mfma16(pa.v, vb8.v, oacc[dc]);
        }
        __builtin_amdgcn_s_setprio(0);
    }

    // ---- store O (scaled by 1/(l*sqrt(768))) ----
    float linv[4];
    #pragma unroll
    for (int rr = 0; rr < 4; rr++)
        linv[rr] = INV_SQRT_EMB / __shfl(l_run, 4 * g + rr, 64);
    #pragma unroll
    for (int rr = 0; rr < 4; rr++) {
        const int row = q0 + w * 16 + 4 * g + rr;
        if (row < NTOK) {
            u16* dst = o + base + (long)row * EMB;
            #pragma unroll
            for (int dc = 0; dc < 24; dc++)
                dst[dc * 16 + l15] = f2bf(oacc[dc][rr] * linv[rr]);
        }
    }
}

// ---------------- LN2 then residual-add into t (bf16) ----------------
__global__ __launch_bounds__(256)
void ln_add_kernel(const float* __restrict__ in, u16* __restrict__ t,
                   const float* __restrict__ g, const float* __restrict__ be)
{
    __shared__ float red[256];
    const int row = blockIdx.x, tid = threadIdx.x;
    const float* x = in + (long)row * EMB;
    const float v0 = x[tid], v1 = x[tid + 256], v2 = x[tid + 512];
    const float mu = blk_sum(v0 + v1 + v2, red, tid) * (1.f / EMB);
    const float d0 = v0 - mu, d1 = v1 - mu, d2 = v2 - mu;
    const float var = blk_sum(d0 * d0 + d1 * d1 + d2 * d2, red, tid) * (1.f / EMB);
    const float rs = rsqrtf(var + LN_EPS);
    u16* o = t + (long)row * EMB;
    o[tid]       = f2bf(bf2f(o[tid])       + d0 * rs * g[tid]       + be[tid]);
    o[tid + 256] = f2bf(bf2f(o[tid + 256]) + d1 * rs * g[tid + 256] + be[tid + 256]);
    o[tid + 512] = f2bf(bf2f(o[tid + 512]) + d2 * rs * g[tid + 512] + be[tid + 512]);
}

// ---------------- mean over tokens ----------------
__global__ __launch_bounds__(128)
void meanpool_kernel(const u16* __restrict__ t, float* __restrict__ m)
{
    const int b = blockIdx.y;
    const int e = blockIdx.x * 128 + threadIdx.x;
    const u16* p = t + (long)b * NTOK * EMB + e;
    float s = 0.f;
    for (int j = 0; j < NTOK; j++) s += bf2f(p[(long)j * EMB]);
    m[b * EMB + e] = s * (1.f / NTOK);
}

// ---------------- LN3 + final Linear (fp32) ----------------
__global__ __launch_bounds__(256)
void final_kernel(const float* __restrict__ m, const float* __restrict__ g,
                  const float* __restrict__ be, const float* __restrict__ Wf,
                  const float* __restrict__ bf, float* __restrict__ out)
{
    __shared__ float red[256];
    __shared__ float mln[EMB];
    const int b = blockIdx.x, tid = threadIdx.x;
    const float* x = m + b * EMB;
    const float v0 = x[tid], v1 = x[tid + 256], v2 = x[tid + 512];
    const float mu = blk_sum(v0 + v1 + v2, red, tid) * (1.f / EMB);
    const float d0 = v0 - mu, d1 = v1 - mu, d2 = v2 - mu;
    const float var = blk_sum(d0 * d0 + d1 * d1 + d2 * d2, red, tid) * (1.f / EMB);
    const float rs = rsqrtf(var + LN_EPS);
    mln[tid]       = d0 * rs * g[tid]       + be[tid];
    mln[tid + 256] = d1 * rs * g[tid + 256] + be[tid + 256];
    mln[tid + 512] = d2 * rs * g[tid + 512] + be[tid + 512];
    __syncthreads();
    #pragma unroll
    for (int s = 0; s < 3; s++) {
        const int e = tid + s * 256;
        float acc = bf[e];
        #pragma unroll 8
        for (int kk = 0; kk < EMB; kk++) acc += mln[kk] * Wf[(long)kk * EMB + e];
        out[(long)b * EMB + e] = acc;
    }
}

extern "C" void kernel_launch(void* const* d_in, const int* in_sizes, int n_in,
                              void* d_out, int out_size, void* d_ws, size_t ws_size,
                              hipStream_t stream) {
    const float* x      = (const float*)d_in[0];
    const float* text   = (const float*)d_in[1];
    const float* Wpatch = (const float*)d_in[2];
    const float* bpatch = (const float*)d_in[3];
    const float* cls    = (const float*)d_in[4];
    const float* g1  = (const float*)d_in[5];
    const float* be1 = (const float*)d_in[6];
    const float* Wq  = (const float*)d_in[7];
    const float* bq  = (const float*)d_in[8];
    const float* Wk  = (const float*)d_in[9];
    const float* bk  = (const float*)d_in[10];
    const float* Wv  = (const float*)d_in[11];
    const float* bv  = (const float*)d_in[12];
    const float* Wp  = (const float*)d_in[13];
    const float* bp  = (const float*)d_in[14];
    const float* g2  = (const float*)d_in[15];
    const float* be2 = (const float*)d_in[16];
    const float* g3  = (const float*)d_in[17];
    const float* be3 = (const float*)d_in[18];
    const float* Wf  = (const float*)d_in[19];
    const float* bf  = (const float*)d_in[20];

    // ws layout (~167 MB): t | h | q | k | v (bf16, 5 x 32.1 MB); o2 fp32 over k+v;
    // Wt bf16 (5 x 1.18 MB); mp fp32
    char* ws = (char*)d_ws;
    const size_t S2 = (size_t)MROWS * EMB * 2;   // 32,145,408
    u16*   t   = (u16*)ws;
    u16*   hb  = (u16*)(ws + S2);
    u16*   qb  = (u16*)(ws + 2 * S2);
    u16*   kbf = (u16*)(ws + 3 * S2);
    u16*   vbf = (u16*)(ws + 4 * S2);
    float* o2  = (float*)(ws + 3 * S2);
    u16*   wt  = (u16*)(ws + 5 * S2);
    float* mp  = (float*)(ws + 5 * S2 + (size_t)5 * EMB * EMB * 2);
    const size_t WTS = (size_t)EMB * EMB;

    // 1) weights -> bf16 transposed
    wt_kernel<<<dim3(24, 24, 5), 256, 0, stream>>>(Wpatch, Wq, Wk, Wv, Wp, wt);
    // 2) cls + text rows of t
    fill_rows_kernel<<<dim3(NTEXT + 1, NBATCH), 256, 0, stream>>>(cls, text, t);
    // 3) patch embed -> t
    patch_mfma<<<dim3(6, NBATCH * NPATCH / 128), 256, 0, stream>>>(x, wt, bpatch, t);
    // 4) h = LN1(t) bf16
    ln_h_kernel<<<MROWS, 256, 0, stream>>>(t, hb, g1, be1);
    // 5) QKV (dense v2, 984 blocks each)
    const int DLDS = 2 * 2 * DTILE_B;   // 65536
    dense_gemm<true><<<984, 256, DLDS, stream>>>(hb, wt + 1 * WTS, bq, qb,  MROWS);
    dense_gemm<true><<<984, 256, DLDS, stream>>>(hb, wt + 2 * WTS, bk, kbf, MROWS);
    dense_gemm<true><<<984, 256, DLDS, stream>>>(hb, wt + 3 * WTS, bv, vbf, MROWS);
    // 6) flash attention v3 (o over q)
    flash_mfma<<<704, 256, FLASH_LDS, stream>>>(qb, kbf, vbf, qb);
    // 7) proj -> o2 fp32
    dense_gemm<false><<<984, 256, DLDS, stream>>>(qb, wt + 4 * WTS, bp, o2, MROWS);
    // 8) t += LN2(o2)
    ln_add_kernel<<<MROWS, 256, 0, stream>>>(o2, t, g2, be2);
    // 9) mean pool
    meanpool_kernel<<<dim3(6, NBATCH), 128, 0, stream>>>(t, mp);
    // 10) LN3 + final linear
    final_kernel<<<NBATCH, 256, 0, stream>>>(mp, g3, be3, Wf, bf, (float*)d_out);
}

// Round 6
// 665.612 us; speedup vs baseline: 4.8570x; 1.1479x over previous
//
#include <hip/hip_runtime.h>
#include <hip/hip_bf16.h>
#include <math.h>

#define EMB 768
#define NTOK 654
#define NPATCH 576
#define NTEXT 77
#define NBATCH 32
#define HD 384
#define MROWS (NBATCH * NTOK)   // 20928
#define LN_EPS 1e-5f
#define INV_SQRT_EMB 0.03608439182435161f

typedef unsigned int u32;
typedef unsigned short u16;
typedef float f32x4 __attribute__((ext_vector_type(4)));
typedef __bf16 bf16x8 __attribute__((ext_vector_type(8)));

union BF8 { uint4 u4; u32 w[4]; bf16x8 v; };

// async global->LDS, 16B per lane; dest = wave-uniform base + lane*16
#define GLL(gsrc, ldst) __builtin_amdgcn_global_load_lds( \
    (const __attribute__((address_space(1))) unsigned int*)(gsrc), \
    (__attribute__((address_space(3))) unsigned int*)(ldst), 16, 0, 0)

// ---------------- helpers ----------------
__device__ __forceinline__ float bf2f(u16 u) {
    union { u32 i; float f; } x; x.i = ((u32)u) << 16; return x.f;
}
__device__ __forceinline__ u16 f2bf(float f) {  // RTNE
    union { float f; u32 i; } x; x.f = f;
    u32 r = x.i + 0x7fffu + ((x.i >> 16) & 1u);
    return (u16)(r >> 16);
}
__device__ __forceinline__ u32 pk2(float lo, float hi) {
    return (u32)f2bf(lo) | ((u32)f2bf(hi) << 16);
}
__device__ __forceinline__ float blk_sum(float v, float* red, int tid) {
    red[tid] = v; __syncthreads();
    #pragma unroll
    for (int s = 128; s > 0; s >>= 1) {
        if (tid < s) red[tid] += red[tid + s];
        __syncthreads();
    }
    float r = red[0]; __syncthreads();
    return r;
}
__device__ __forceinline__ f32x4 mfma16(bf16x8 a, bf16x8 b, f32x4 c) {
    return __builtin_amdgcn_mfma_f32_16x16x32_bf16(a, b, c, 0, 0, 0);
}

// ---------------- weight transpose + bf16: Wt[n][k] = bf16(W[k][n]) ----------------
__global__ __launch_bounds__(256)
void wt_kernel(const float* __restrict__ W0, const float* __restrict__ W1,
               const float* __restrict__ W2, const float* __restrict__ W3,
               const float* __restrict__ W4, u16* __restrict__ dst)
{
    __shared__ float tile[32][33];
    const int z = blockIdx.z;
    const float* W = (z == 0) ? W0 : (z == 1) ? W1 : (z == 2) ? W2 : (z == 3) ? W3 : W4;
    u16* o = dst + (size_t)z * EMB * EMB;
    const int bi = blockIdx.y, bj = blockIdx.x;
    const int r = threadIdx.x >> 5, c = threadIdx.x & 31;
    #pragma unroll
    for (int i = 0; i < 4; i++)
        tile[r + i * 8][c] = W[(long)(bi * 32 + r + i * 8) * EMB + bj * 32 + c];
    __syncthreads();
    #pragma unroll
    for (int i = 0; i < 4; i++) {
        const int rr = r + i * 8;
        o[(long)(bj * 32 + rr) * EMB + bi * 32 + c] = f2bf(tile[c][rr]);
    }
}

// ---------------- fill cls + text rows of t (bf16) ----------------
__global__ __launch_bounds__(256)
void fill_rows_kernel(const float* __restrict__ cls, const float* __restrict__ text,
                      u16* __restrict__ t)
{
    const int b = blockIdx.y, r = blockIdx.x;
    const int tid = threadIdx.x;
    const long trow = (long)b * NTOK + (r == 0 ? 0 : NPATCH + r);
    const float* src = (r == 0) ? cls : text + ((long)b * NTEXT + (r - 1)) * EMB;
    u16* dst = t + trow * EMB;
    #pragma unroll
    for (int s = 0; s < 3; s++) dst[tid + s * 256] = f2bf(src[tid + s * 256]);
}

// ---------------- im2col: x[32,3,384,384] fp32 -> patches[18432][768] bf16 -----------
// block = one x row (bb, c, p1, hh): 384 threads = cols; writes 3 u16 per thread? no:
// thread t handles col t; for c in 0..2 reads plane c -> 3 consecutive bf16 out elems.
__global__ __launch_bounds__(384)
void im2col_kernel(const float* __restrict__ x, u16* __restrict__ patches)
{
    const int t = threadIdx.x;              // 0..383 = image column
    const int hh = blockIdx.y;              // 0..23
    const int gx = blockIdx.x;              // 0..511 = bb*16 + p1
    const int bb = gx >> 4, p1 = gx & 15;
    const int ww = t >> 4, p2 = t & 15;
    u16* dst = patches + ((long)(bb * NPATCH + hh * 24 + ww) * EMB) + (p1 * 16 + p2) * 3;
    #pragma unroll
    for (int c = 0; c < 3; c++) {
        const float f = x[((long)(bb * 3 + c) * 384 + hh * 16 + p1) * 384 + t];
        dst[c] = f2bf(f);
    }
}

// ---------------- LN1: t(bf16) -> h(bf16) ----------------
__global__ __launch_bounds__(256)
void ln_h_kernel(const u16* __restrict__ t, u16* __restrict__ h,
                 const float* __restrict__ g, const float* __restrict__ be)
{
    __shared__ float red[256];
    const int row = blockIdx.x, tid = threadIdx.x;
    const u16* xp = t + (long)row * EMB;
    const float v0 = bf2f(xp[tid]), v1 = bf2f(xp[tid + 256]), v2 = bf2f(xp[tid + 512]);
    const float mu = blk_sum(v0 + v1 + v2, red, tid) * (1.f / EMB);
    const float d0 = v0 - mu, d1 = v1 - mu, d2 = v2 - mu;
    const float var = blk_sum(d0 * d0 + d1 * d1 + d2 * d2, red, tid) * (1.f / EMB);
    const float rs = rsqrtf(var + LN_EPS);
    u16* o = h + (long)row * EMB;
    o[tid]       = f2bf(d0 * rs * g[tid]       + be[tid]);
    o[tid + 256] = f2bf(d1 * rs * g[tid + 256] + be[tid + 256]);
    o[tid + 512] = f2bf(d2 * rs * g[tid + 512] + be[tid + 512]);
}

// ---------------- dense MFMA GEMM v3: GLL dbuf + counted vmcnt + RAW barriers --------
// C = A(bf16,[M][768]) @ Wt^T + bias. BK=64. nb column-blocks; z = cb/6 selects
// (Bt matrix, bias, out). REMAP remaps C rows for the patch-embed path.
#define DBK 64
#define DTILE_B (128 * DBK * 2)   // 16384 B per operand tile

template<bool OBF16, bool REMAP>
__global__ __launch_bounds__(256)
void dense_gemm(const u16* __restrict__ A, const u16* __restrict__ Bt,
                const float* __restrict__ b0, const float* __restrict__ b1,
                const float* __restrict__ b2,
                void* __restrict__ C0, void* __restrict__ C1, void* __restrict__ C2,
                int M, int nb)
{
    extern __shared__ char sm[];   // [2][A|B][128][64]u16 = 65536 B
    const int cpx = gridDim.x >> 3;
    const int wg = blockIdx.x;
    const int work = (wg & 7) * cpx + (wg >> 3);
    const int cb = work % nb;
    const int m0 = (work / nb) * 128;
    const int z  = cb / 6;
    const int n0 = (cb % 6) * 128;
    const u16* Btz = Bt + (size_t)z * EMB * EMB;
    const float* bias = (z == 0) ? b0 : (z == 1) ? b1 : b2;
    void* Cz = (z == 0) ? C0 : (z == 1) ? C1 : C2;

    const int tid = threadIdx.x;
    const int lane = tid & 63, w = tid >> 6, wr = w >> 1, wc = w & 1;
    const int l15 = lane & 15, g = lane >> 4;
    const int wbase = (tid & ~63);

    f32x4 acc[4][4] = {};

    auto stage = [&](int k0, int buf) {
        char* dst = sm + buf * 2 * DTILE_B;
        #pragma unroll
        for (int c = 0; c < 4; c++) {
            const int idx = c * 256 + tid;
            const int r = idx >> 3, s = idx & 7;
            const int gs = s ^ (r & 7);
            const int ar = min(m0 + r, M - 1);
            GLL(A + (long)ar * EMB + k0 + gs * 8, dst + (c * 256 + wbase) * 16);
        }
        #pragma unroll
        for (int c = 0; c < 4; c++) {
            const int idx = c * 256 + tid;
            const int r = idx >> 3, s = idx & 7;
            const int gs = s ^ (r & 7);
            GLL(Btz + (long)(n0 + r) * EMB + k0 + gs * 8,
                dst + DTILE_B + (c * 256 + wbase) * 16);
        }
    };

    stage(0, 0);
    for (int t = 0; t < 12; t++) {
        if (t < 11) {
            stage((t + 1) * DBK, (t + 1) & 1);
            asm volatile("s_waitcnt vmcnt(8)" ::: "memory");   // tile t landed; t+1 in flight
        } else {
            asm volatile("s_waitcnt vmcnt(0)" ::: "memory");
        }
        __builtin_amdgcn_s_barrier();          // all waves' tile-t loads landed
        __builtin_amdgcn_sched_barrier(0);
        const char* Asb = sm + (t & 1) * 2 * DTILE_B;
        const char* Bsb = Asb + DTILE_B;
        #pragma unroll
        for (int ks = 0; ks < 2; ks++) {
            BF8 af[4], bfr[4];
            #pragma unroll
            for (int mi = 0; mi < 4; mi++) {
                const int row = wr * 64 + mi * 16 + l15;
                const int slot = (ks * 4 + g) ^ (row & 7);
                af[mi].u4 = *(const uint4*)(Asb + row * 128 + slot * 16);
            }
            #pragma unroll
            for (int nj = 0; nj < 4; nj++) {
                const int row = wc * 64 + nj * 16 + l15;
                const int slot = (ks * 4 + g) ^ (row & 7);
                bfr[nj].u4 = *(const uint4*)(Bsb + row * 128 + slot * 16);
            }
            __builtin_amdgcn_s_setprio(1);
            #pragma unroll
            for (int mi = 0; mi < 4; mi++)
                #pragma unroll
                for (int nj = 0; nj < 4; nj++)
                    acc[mi][nj] = mfma16(af[mi].v, bfr[nj].v, acc[mi][nj]);
            __builtin_amdgcn_s_setprio(0);
        }
        __builtin_amdgcn_s_barrier();          // all waves done reading buf t&1
        __builtin_amdgcn_sched_barrier(0);
    }

    float bv[4];
    #pragma unroll
    for (int nj = 0; nj < 4; nj++) bv[nj] = bias[n0 + wc * 64 + nj * 16 + l15];
    #pragma unroll
    for (int mi = 0; mi < 4; mi++) {
        #pragma unroll
        for (int rr = 0; rr < 4; rr++) {
            const int r = m0 + wr * 64 + mi * 16 + 4 * g + rr;
            if (r >= M) continue;
            long orow = r;
            if (REMAP) orow = (long)(r / NPATCH) * NTOK + 1 + (r % NPATCH);
            #pragma unroll
            for (int nj = 0; nj < 4; nj++) {
                const int cc = n0 + wc * 64 + nj * 16 + l15;
                const float val = acc[mi][nj][rr] + bv[nj];
                if (OBF16) ((u16*)Cz)[orow * EMB + cc] = f2bf(val);
                else       ((float*)Cz)[orow * EMB + cc] = val;
            }
        }
    }
}

// ---------------- flash attention v4: 8 waves, all-reg staging, raw barriers ---------
// 512 thr = 8 waves, each wave 16 q-rows (128 q/block). KV tiles of 32 keys.
// K: regs -> ds_write XOR-swizzled [32][384]; V: regs -> ds_write transposed Vt[384][36].
// Single LDS buffers (62464 B) -> 2 blocks/CU. Two raw barriers per tile:
//   (A) top: WAR gate (writes of tile t vs reads of t-1), after vmcnt(0) for regs;
//   (B) after lgkmcnt(0): all waves' K/V LDS writes visible -> compute.
#define VTLD 36   // Vt row stride (u16), 72 B (b64-aligned, conflict-free reads)
#define PSLD 40   // Ps row stride (u16)
#define FLASH_LDS (32 * 384 * 2 + 384 * VTLD * 2 + 8 * 16 * PSLD * 2)  // 62464

__global__ __launch_bounds__(512, 2)
void flash_mfma(const u16* __restrict__ q, const u16* __restrict__ k,
                const u16* __restrict__ v, u16* __restrict__ o)
{
    extern __shared__ char smem[];
    u16* Ks = (u16*)smem;                            // [32][384] swizzled
    u16* Vt = (u16*)(smem + 32 * 384 * 2);           // [384][VTLD]
    char* Ps = smem + 32 * 384 * 2 + 384 * VTLD * 2; // 8 waves x [16][PSLD]

    // XCD-bijective: 384 = 8 * 48; 6 consecutive works share one (b,h)
    const int wg = blockIdx.x;
    const int work = (wg & 7) * 48 + (wg >> 3);
    const int bh = work / 6, qblk = work % 6;
    const int b = bh >> 1, h = bh & 1;
    const int q0 = qblk * 128;
    const int tid = threadIdx.x;
    const int lane = tid & 63, w = tid >> 6;
    const int l15 = lane & 15, g = lane >> 4;
    const long base = (long)b * NTOK * EMB + h * HD;

    // Q fragments in registers: 12 d-steps of 32
    BF8 qf[12];
    {
        const int qrow = q0 + w * 16 + l15;
        if (qrow < NTOK) {
            const u16* src = q + base + (long)qrow * EMB;
            #pragma unroll
            for (int ds = 0; ds < 12; ds++)
                qf[ds].u4 = *(const uint4*)(src + ds * 32 + g * 8);
        } else {
            #pragma unroll
            for (int ds = 0; ds < 12; ds++) qf[ds].u4 = make_uint4(0, 0, 0, 0);
        }
    }

    // K reg staging: 3 granules/thread (1536 = 3*512)
    int kR[3], kGr[3];
    #pragma unroll
    for (int c = 0; c < 3; c++) {
        const int idx = c * 512 + tid;
        kR[c] = idx / 48; kGr[c] = idx % 48;
    }
    uint4 kregs[3];
    auto loadK = [&](int kv0) {
        #pragma unroll
        for (int c = 0; c < 3; c++)
            kregs[c] = *(const uint4*)(k + base +
                (long)min(kv0 + kR[c], NTOK - 1) * EMB + kGr[c] * 8);
    };
    auto writeK = [&]() {
        #pragma unroll
        for (int c = 0; c < 3; c++) {
            const int slot = (kGr[c] & ~7) | ((kGr[c] & 7) ^ (kR[c] & 7));
            *(uint4*)&Ks[kR[c] * 384 + slot * 8] = kregs[c];
        }
    };

    // V reg staging (tid<384): key pair kp, d-segments dsg0 and dsg0+24
    const int kp = tid & 15, dsg0 = tid >> 4;  // dsg0 valid 0..23 when tid<384
    uint4 va0, vb0, va1, vb1;
    auto loadV = [&](int kv0) {
        const int kr0 = kv0 + 2 * kp;
        const u16* v0p = v + base + (long)min(kr0, NTOK - 1) * EMB;
        const u16* v1p = v + base + (long)min(kr0 + 1, NTOK - 1) * EMB;
        va0 = *(const uint4*)(v0p + dsg0 * 8);
        vb0 = *(const uint4*)(v1p + dsg0 * 8);
        va1 = *(const uint4*)(v0p + (dsg0 + 24) * 8);
        vb1 = *(const uint4*)(v1p + (dsg0 + 24) * 8);
    };
    auto writeV = [&](int kv0) {
        const int kr0 = kv0 + 2 * kp;
        const bool ok0 = kr0 < NTOK, ok1 = (kr0 + 1) < NTOK;
        const u16* a0 = (const u16*)&va0; const u16* b0p = (const u16*)&vb0;
        const u16* a1 = (const u16*)&va1; const u16* b1p = (const u16*)&vb1;
        #pragma unroll
        for (int e = 0; e < 8; e++) {
            const u32 lo0 = ok0 ? (u32)a0[e] : 0u, hi0 = ok1 ? (u32)b0p[e] : 0u;
            const u32 lo1 = ok0 ? (u32)a1[e] : 0u, hi1 = ok1 ? (u32)b1p[e] : 0u;
            *(u32*)&Vt[(dsg0 * 8 + e) * VTLD + 2 * kp] = lo0 | (hi0 << 16);
            *(u32*)&Vt[((dsg0 + 24) * 8 + e) * VTLD + 2 * kp] = lo1 | (hi1 << 16);
        }
    };

    float m_run = -3.0e38f, l_run = 0.f;
    f32x4 oacc[24] = {};

    loadK(0);
    if (tid < 384) loadV(0);

    for (int kt = 0; kt < 21; kt++) {
        const int kv0 = kt * 32;
        asm volatile("s_waitcnt vmcnt(0)" ::: "memory");  // K/V(kt) regs ready
        __builtin_amdgcn_s_barrier();                      // all waves done compute(kt-1)
        __builtin_amdgcn_sched_barrier(0);
        writeK();
        if (tid < 384) writeV(kv0);
        if (kt < 20) {
            loadK(kv0 + 32);
            if (tid < 384) loadV(kv0 + 32);
        }
        asm volatile("s_waitcnt lgkmcnt(0)" ::: "memory"); // own LDS writes done
        __builtin_amdgcn_s_barrier();                      // all waves' K/V visible
        __builtin_amdgcn_sched_barrier(0);

        // ---- S^T = K @ Q^T (swizzled reads) ----
        f32x4 sacc[2] = {};
        __builtin_amdgcn_s_setprio(1);
        #pragma unroll
        for (int ds = 0; ds < 12; ds++) {
            const int idx = ds * 4 + g;
            const int slot = (idx & ~7) | ((idx & 7) ^ (l15 & 7));
            BF8 ak0, ak1;
            ak0.u4 = *(const uint4*)((const char*)Ks + l15 * 768 + slot * 16);
            ak1.u4 = *(const uint4*)((const char*)Ks + (16 + l15) * 768 + slot * 16);
            sacc[0] = mfma16(ak0.v, qf[ds].v, sacc[0]);
            sacc[1] = mfma16(ak1.v, qf[ds].v, sacc[1]);
        }
        __builtin_amdgcn_s_setprio(0);

        // ---- mask + online softmax (per q = l15) ----
        float pe[2][4];
        float mx = -3.0e38f;
        #pragma unroll
        for (int kb = 0; kb < 2; kb++)
            #pragma unroll
            for (int rr = 0; rr < 4; rr++) {
                float s = sacc[kb][rr];
                if (kv0 + kb * 16 + 4 * g + rr >= NTOK) s = -1e30f;
                pe[kb][rr] = s;
                mx = fmaxf(mx, s);
            }
        mx = fmaxf(mx, __shfl_xor(mx, 16, 64));
        mx = fmaxf(mx, __shfl_xor(mx, 32, 64));
        const float m_new = fmaxf(m_run, mx);
        const float corr = __expf(m_run - m_new);
        float psum = 0.f;
        #pragma unroll
        for (int kb = 0; kb < 2; kb++)
            #pragma unroll
            for (int rr = 0; rr < 4; rr++) {
                pe[kb][rr] = __expf(pe[kb][rr] - m_new);
                psum += pe[kb][rr];
            }
        psum += __shfl_xor(psum, 16, 64);
        psum += __shfl_xor(psum, 32, 64);
        l_run = l_run * corr + psum;
        m_run = m_new;

        // ---- canonicalize P via per-wave LDS roundtrip ----
        {
            u32* pw = (u32*)(Ps + w * (16 * PSLD * 2) + l15 * (PSLD * 2));
            pw[g * 2]         = pk2(pe[0][0], pe[0][1]);
            pw[g * 2 + 1]     = pk2(pe[0][2], pe[0][3]);
            pw[8 + g * 2]     = pk2(pe[1][0], pe[1][1]);
            pw[8 + g * 2 + 1] = pk2(pe[1][2], pe[1][3]);
        }
        asm volatile("s_waitcnt lgkmcnt(0)" ::: "memory");
        __builtin_amdgcn_sched_barrier(0);
        BF8 pa;
        pa.u4 = *(const uint4*)(Ps + w * (16 * PSLD * 2) + l15 * (PSLD * 2) + g * 16);

        float cb4[4];
        #pragma unroll
        for (int rr = 0; rr < 4; rr++) cb4[rr] = __shfl(corr, 4 * g + rr, 64);

        // ---- PV: O[q][dv] += P @ V ----
        __builtin_amdgcn_s_setprio(1);
        #pragma unroll
        for (int dc = 0; dc < 24; dc++) {
            #pragma unroll
            for (int rr = 0; rr < 4; rr++) oacc[dc][rr] *= cb4[rr];
            const u16* vp = &Vt[(dc * 16 + l15) * VTLD + g * 8];
            const uint2 lo = *(const uint2*)vp;
            const uint2 hi = *(const uint2*)(vp + 4);
            BF8 vb8;
            vb8.w[0] = lo.x; vb8.w[1] = lo.y; vb8.w[2] = hi.x; vb8.w[3] = hi.y;
            oacc[dc] = mfma16(pa.v, vb8.v, oacc[dc]);
        }
        __builtin_amdgcn_s_setprio(0);
    }

    // ---- store O (scaled by 1/(l*sqrt(768))) ----
    float linv[4];
    #pragma unroll
    for (int rr = 0; rr < 4; rr++)
        linv[rr] = INV_SQRT_EMB / __shfl(l_run, 4 * g + rr, 64);
    #pragma unroll
    for (int rr = 0; rr < 4; rr++) {
        const int row = q0 + w * 16 + 4 * g + rr;
        if (row < NTOK) {
            u16* dst = o + base + (long)row * EMB;
            #pragma unroll
            for (int dc = 0; dc < 24; dc++)
                dst[dc * 16 + l15] = f2bf(oacc[dc][rr] * linv[rr]);
        }
    }
}

// ---------------- LN2 then residual-add into t (bf16) ----------------
__global__ __launch_bounds__(256)
void ln_add_kernel(const float* __restrict__ in, u16* __restrict__ t,
                   const float* __restrict__ g, const float* __restrict__ be)
{
    __shared__ float red[256];
    const int row = blockIdx.x, tid = threadIdx.x;
    const float* x = in + (long)row * EMB;
    const float v0 = x[tid], v1 = x[tid + 256], v2 = x[tid + 512];
    const float mu = blk_sum(v0 + v1 + v2, red, tid) * (1.f / EMB);
    const float d0 = v0 - mu, d1 = v1 - mu, d2 = v2 - mu;
    const float var = blk_sum(d0 * d0 + d1 * d1 + d2 * d2, red, tid) * (1.f / EMB);
    const float rs = rsqrtf(var + LN_EPS);
    u16* o = t + (long)row * EMB;
    o[tid]       = f2bf(bf2f(o[tid])       + d0 * rs * g[tid]       + be[tid]);
    o[tid + 256] = f2bf(bf2f(o[tid + 256]) + d1 * rs * g[tid + 256] + be[tid + 256]);
    o[tid + 512] = f2bf(bf2f(o[tid + 512]) + d2 * rs * g[tid + 512] + be[tid + 512]);
}

// ---------------- mean over tokens ----------------
__global__ __launch_bounds__(128)
void meanpool_kernel(const u16* __restrict__ t, float* __restrict__ m)
{
    const int b = blockIdx.y;
    const int e = blockIdx.x * 128 + threadIdx.x;
    const u16* p = t + (long)b * NTOK * EMB + e;
    float s = 0.f;
    for (int j = 0; j < NTOK; j++) s += bf2f(p[(long)j * EMB]);
    m[b * EMB + e] = s * (1.f / NTOK);
}

// ---------------- LN3 + final Linear (fp32) ----------------
__global__ __launch_bounds__(256)
void final_kernel(const float* __restrict__ m, const float* __restrict__ g,
                  const float* __restrict__ be, const float* __restrict__ Wf,
                  const float* __restrict__ bf, float* __restrict__ out)
{
    __shared__ float red[256];
    __shared__ float mln[EMB];
    const int b = blockIdx.x, tid = threadIdx.x;
    const float* x = m + b * EMB;
    const float v0 = x[tid], v1 = x[tid + 256], v2 = x[tid + 512];
    const float mu = blk_sum(v0 + v1 + v2, red, tid) * (1.f / EMB);
    const float d0 = v0 - mu, d1 = v1 - mu, d2 = v2 - mu;
    const float var = blk_sum(d0 * d0 + d1 * d1 + d2 * d2, red, tid) * (1.f / EMB);
    const float rs = rsqrtf(var + LN_EPS);
    mln[tid]       = d0 * rs * g[tid]       + be[tid];
    mln[tid + 256] = d1 * rs * g[tid + 256] + be[tid + 256];
    mln[tid + 512] = d2 * rs * g[tid + 512] + be[tid + 512];
    __syncthreads();
    #pragma unroll
    for (int s = 0; s < 3; s++) {
        const int e = tid + s * 256;
        float acc = bf[e];
        #pragma unroll 8
        for (int kk = 0; kk < EMB; kk++) acc += mln[kk] * Wf[(long)kk * EMB + e];
        out[(long)b * EMB + e] = acc;
    }
}

extern "C" void kernel_launch(void* const* d_in, const int* in_sizes, int n_in,
                              void* d_out, int out_size, void* d_ws, size_t ws_size,
                              hipStream_t stream) {
    const float* x      = (const float*)d_in[0];
    const float* text   = (const float*)d_in[1];
    const float* Wpatch = (const float*)d_in[2];
    const float* bpatch = (const float*)d_in[3];
    const float* cls    = (const float*)d_in[4];
    const float* g1  = (const float*)d_in[5];
    const float* be1 = (const float*)d_in[6];
    const float* Wq  = (const float*)d_in[7];
    const float* bq  = (const float*)d_in[8];
    const float* Wk  = (const float*)d_in[9];
    const float* bk  = (const float*)d_in[10];
    const float* Wv  = (const float*)d_in[11];
    const float* bv  = (const float*)d_in[12];
    const float* Wp  = (const float*)d_in[13];
    const float* bp  = (const float*)d_in[14];
    const float* g2  = (const float*)d_in[15];
    const float* be2 = (const float*)d_in[16];
    const float* g3  = (const float*)d_in[17];
    const float* be3 = (const float*)d_in[18];
    const float* Wf  = (const float*)d_in[19];
    const float* bf  = (const float*)d_in[20];

    // ws layout (~167 MB): t | h | q | k | v (bf16, 5 x 32.1 MB)
    //  patches bf16 (28.3 MB) ALIASES q (dead until QKV writes it)
    //  o2 fp32 (64.3 MB) overlaps k+v (dead after flash)
    //  Wt bf16 (5 x 1.18 MB) | mp fp32
    char* ws = (char*)d_ws;
    const size_t S2 = (size_t)MROWS * EMB * 2;   // 32,145,408
    u16*   t    = (u16*)ws;
    u16*   hb   = (u16*)(ws + S2);
    u16*   qb   = (u16*)(ws + 2 * S2);
    u16*   kbf  = (u16*)(ws + 3 * S2);
    u16*   vbf  = (u16*)(ws + 4 * S2);
    float* o2   = (float*)(ws + 3 * S2);
    u16*   wt   = (u16*)(ws + 5 * S2);
    float* mp   = (float*)(ws + 5 * S2 + (size_t)5 * EMB * EMB * 2);
    u16*   pat  = qb;   // im2col output aliases q
    const size_t WTS = (size_t)EMB * EMB;
    const int DLDS = 2 * 2 * DTILE_B;   // 65536

    // 1) weights -> bf16 transposed
    wt_kernel<<<dim3(24, 24, 5), 256, 0, stream>>>(Wpatch, Wq, Wk, Wv, Wp, wt);
    // 2) cls + text rows of t
    fill_rows_kernel<<<dim3(NTEXT + 1, NBATCH), 256, 0, stream>>>(cls, text, t);
    // 3) im2col -> patches (aliases q)
    im2col_kernel<<<dim3(512, 24), 384, 0, stream>>>(x, pat);
    // 4) patch embed: dense GEMM with row remap -> t   (864 = 8*108 blocks)
    dense_gemm<true, true><<<864, 256, DLDS, stream>>>(
        pat, wt, bpatch, bpatch, bpatch, t, t, t, NBATCH * NPATCH, 6);
    // 5) h = LN1(t)
    ln_h_kernel<<<MROWS, 256, 0, stream>>>(t, hb, g1, be1);
    // 6) fused QKV: nb=18, z selects Wq/Wk/Wv  (2952 = 8*369 blocks)
    dense_gemm<true, false><<<2952, 256, DLDS, stream>>>(
        hb, wt + WTS, bq, bk, bv, qb, kbf, vbf, MROWS, 18);
    // 7) flash attention v4 (o over q)
    flash_mfma<<<384, 512, FLASH_LDS, stream>>>(qb, kbf, vbf, qb);
    // 8) proj -> o2 fp32   (984 = 8*123 blocks)
    dense_gemm<false, false><<<984, 256, DLDS, stream>>>(
        qb, wt + 4 * WTS, bp, bp, bp, o2, o2, o2, MROWS, 6);
    // 9) t += LN2(o2)
    ln_add_kernel<<<MROWS, 256, 0, stream>>>(o2, t, g2, be2);
    // 10) mean pool
    meanpool_kernel<<<dim3(6, NBATCH), 128, 0, stream>>>(t, mp);
    // 11) LN3 + final linear
    final_kernel<<<NBATCH, 256, 0, stream>>>(mp, g3, be3, Wf, bf, (float*)d_out);
}